// Round 1
// baseline (602.772 us; speedup 1.0000x reference)
//
#include <hip/hip_runtime.h>
#include <math.h>

// Problem constants
#define NB 8
#define NT 16
#define NN 64
#define NF 64
#define NH 1024
#define BT 128          // NB*NT
#define NFK 4096        // NN*NF (K dim of folded score GEMM)

// ws layout (float offsets)
#define WEFF_OFF 0                 // 2*64*4096 = 524288
#define BEFF_OFF 524288            // 2*64 = 128
#define PSEL_OFF 524416            // 2*128*4*64 = 65536
#define IDX_OFF  589952            // 2*128*4 ints

// ---------------------------------------------------------------------------
// K1: fold W_eff[which] (64x4096) = Wscore(64x1024) @ Wproj(1024x4096)
// grid (64 col-tiles, 2 which), 256 threads
// ---------------------------------------------------------------------------
__global__ __launch_bounds__(256) void fold_kernel(
    const float* __restrict__ Wso, const float* __restrict__ Wo,
    const float* __restrict__ Wsd, const float* __restrict__ Wd,
    float* __restrict__ weff)
{
    const int which = blockIdx.y;
    const float* __restrict__ A  = which ? Wsd : Wso;   // 64 x 1024
    const float* __restrict__ Bm = which ? Wd  : Wo;    // 1024 x 4096
    float* __restrict__ out = weff + (size_t)which * 64 * NFK;
    const int c0 = blockIdx.x * 64;

    __shared__ float As[64][68];   // [row r][h']
    __shared__ float Bs[64][68];   // [col c][h']  (transposed store)

    const int t  = threadIdx.x;
    const int tx = t & 15, ty = t >> 4;

    float acc[4][4] = {};

    for (int h0 = 0; h0 < NH; h0 += 64) {
        #pragma unroll
        for (int it = 0; it < 4; ++it) {
            int r = (t >> 4) + it * 16, c4 = (t & 15) * 4;
            *(float4*)&As[r][c4] = *(const float4*)&A[r * NH + h0 + c4];
        }
        #pragma unroll
        for (int it = 0; it < 4; ++it) {
            int h = (t >> 4) + it * 16, c4 = (t & 15) * 4;
            float4 v = *(const float4*)&Bm[(size_t)(h0 + h) * NFK + c0 + c4];
            Bs[c4 + 0][h] = v.x; Bs[c4 + 1][h] = v.y;
            Bs[c4 + 2][h] = v.z; Bs[c4 + 3][h] = v.w;
        }
        __syncthreads();
        #pragma unroll 4
        for (int kk = 0; kk < 64; kk += 4) {
            float4 a4[4], b4[4];
            #pragma unroll
            for (int m = 0; m < 4; ++m) a4[m] = *(const float4*)&As[ty + 16 * m][kk];
            #pragma unroll
            for (int n = 0; n < 4; ++n) b4[n] = *(const float4*)&Bs[tx + 16 * n][kk];
            #pragma unroll
            for (int m = 0; m < 4; ++m)
                #pragma unroll
                for (int n = 0; n < 4; ++n)
                    acc[m][n] += a4[m].x * b4[n].x + a4[m].y * b4[n].y
                               + a4[m].z * b4[n].z + a4[m].w * b4[n].w;
        }
        __syncthreads();
    }
    #pragma unroll
    for (int m = 0; m < 4; ++m)
        #pragma unroll
        for (int n = 0; n < 4; ++n)
            out[(size_t)(ty + 16 * m) * NFK + c0 + tx + 16 * n] = acc[m][n];
}

// ---------------------------------------------------------------------------
// K1b: beff[which][r] = Wscore[r,:]·bproj + bscore[r]   (1 block, 128 thr)
// ---------------------------------------------------------------------------
__global__ void bias_kernel(
    const float* __restrict__ Wso, const float* __restrict__ bo, const float* __restrict__ bso,
    const float* __restrict__ Wsd, const float* __restrict__ bd, const float* __restrict__ bsd,
    float* __restrict__ beff)
{
    int t = threadIdx.x;            // 0..127
    int which = t >> 6, r = t & 63;
    const float* Ws = which ? Wsd : Wso;
    const float* bb = which ? bd  : bo;
    const float* bs = which ? bsd : bso;
    float s = bs[r];
    for (int h = 0; h < NH; ++h) s += Ws[r * NH + h] * bb[h];
    beff[t] = s;
}

// ---------------------------------------------------------------------------
// K2: per (bt, which): scores(64x64) = View(M) @ Weff.T + beff, then
// softmax rows, entropy, top-4 smallest-entropy rows -> psel, idxsel.
// grid (128, 2), 256 threads
// ---------------------------------------------------------------------------
__global__ __launch_bounds__(256) void scores_kernel(
    const float* __restrict__ M, const float* __restrict__ weff,
    const float* __restrict__ beff,
    float* __restrict__ psel, int* __restrict__ idxsel)
{
    const int bt = blockIdx.x, which = blockIdx.y;
    const float* __restrict__ Mbt = M + (size_t)bt * NN * NN * NF;   // 262144
    const float* __restrict__ Wf  = weff + (size_t)which * 64 * NFK;

    __shared__ float As[64][68];
    __shared__ float Bs[64][68];
    __shared__ float Ps[64][68];
    __shared__ float ent[64];
    __shared__ int   sel[4];

    const int t = threadIdx.x;
    const int tx = t & 15, ty = t >> 4;

    float acc[4][4] = {};

    for (int j0 = 0; j0 < NN; ++j0) {
        if (which == 0) {
            // A[i][f] = M[bt, i, j0, f]
            #pragma unroll
            for (int it = 0; it < 4; ++it) {
                int r = (t >> 4) + it * 16, c4 = (t & 15) * 4;
                *(float4*)&As[r][c4] =
                    *(const float4*)&Mbt[(size_t)r * NFK + j0 * NF + c4];
            }
        } else {
            // A[k][f] = M[bt, j0, k, f]  (one contiguous 4096-float block)
            #pragma unroll
            for (int it = 0; it < 4; ++it) {
                int idx4 = t + it * 256;             // float4 index in 1024
                int r = idx4 >> 4, c4 = (idx4 & 15) * 4;
                *(float4*)&As[r][c4] =
                    *(const float4*)&Mbt[(size_t)j0 * NFK + idx4 * 4];
            }
        }
        // B[r][f] = Weff[r, j0*64+f]
        #pragma unroll
        for (int it = 0; it < 4; ++it) {
            int r = (t >> 4) + it * 16, c4 = (t & 15) * 4;
            *(float4*)&Bs[r][c4] = *(const float4*)&Wf[(size_t)r * NFK + j0 * NF + c4];
        }
        __syncthreads();
        #pragma unroll 4
        for (int kk = 0; kk < 64; kk += 4) {
            float4 a4[4], b4[4];
            #pragma unroll
            for (int m = 0; m < 4; ++m) a4[m] = *(const float4*)&As[ty + 16 * m][kk];
            #pragma unroll
            for (int n = 0; n < 4; ++n) b4[n] = *(const float4*)&Bs[tx + 16 * n][kk];
            #pragma unroll
            for (int m = 0; m < 4; ++m)
                #pragma unroll
                for (int n = 0; n < 4; ++n)
                    acc[m][n] += a4[m].x * b4[n].x + a4[m].y * b4[n].y
                               + a4[m].z * b4[n].z + a4[m].w * b4[n].w;
        }
        __syncthreads();
    }

    // epilogue: bias, park scores in LDS
    #pragma unroll
    for (int m = 0; m < 4; ++m)
        #pragma unroll
        for (int n = 0; n < 4; ++n)
            Ps[ty + 16 * m][tx + 16 * n] = acc[m][n] + beff[which * 64 + tx + 16 * n];
    __syncthreads();

    // softmax + entropy per row (threads 0..63, one row each)
    if (t < 64) {
        float mx = -INFINITY;
        for (int l = 0; l < 64; ++l) mx = fmaxf(mx, Ps[t][l]);
        float sum = 0.f;
        for (int l = 0; l < 64; ++l) { float e = expf(Ps[t][l] - mx); Ps[t][l] = e; sum += e; }
        float inv = 1.0f / sum;
        float Hrow = 0.f;
        for (int l = 0; l < 64; ++l) {
            float p = Ps[t][l] * inv; Ps[t][l] = p;
            Hrow -= p * logf(p + 1e-9f);
        }
        ent[t] = Hrow;
    }
    __syncthreads();

    // top-4 smallest entropy, lowest index wins ties (matches lax.top_k)
    if (t == 0) {
        unsigned long long used = 0ull;
        for (int s = 0; s < 4; ++s) {
            float best = INFINITY; int bi = 0;
            for (int r = 0; r < 64; ++r) {
                if ((used >> r) & 1ull) continue;
                if (ent[r] < best) { best = ent[r]; bi = r; }
            }
            used |= 1ull << bi;
            sel[s] = bi;
        }
    }
    __syncthreads();

    if (t < 4) idxsel[((size_t)which * BT + bt) * 4 + t] = sel[t];
    {
        int s = t >> 6, l = t & 63;
        psel[(((size_t)which * BT + bt) * 4 + s) * 64 + l] = Ps[sel[s]][l];
    }
}

// ---------------------------------------------------------------------------
// K3: per bt: out1[i,k,l] = sum_j po[i,j] M[bt,j,k,l]  (i in 4 selected)
//            out[bt, io[i], id[j], k] = sum_l out1[i,k,l] pd[j,l]
// grid 128, 256 threads. d_out pre-zeroed by memset.
// ---------------------------------------------------------------------------
__global__ __launch_bounds__(256) void scatter_kernel(
    const float* __restrict__ M, const float* __restrict__ psel,
    const int* __restrict__ idxsel, float* __restrict__ out)
{
    const int bt = blockIdx.x;
    __shared__ float po[4][64], pd[4][64];
    __shared__ int io[4], id[4];
    __shared__ float o1[4][64][68];   // padded l-stride: 69.6 KB

    const int t = threadIdx.x;
    {
        int s = t >> 6, l = t & 63;
        po[s][l] = psel[(((size_t)0 * BT + bt) * 4 + s) * 64 + l];
        pd[s][l] = psel[(((size_t)1 * BT + bt) * 4 + s) * 64 + l];
    }
    if (t < 4) {
        io[t] = idxsel[((size_t)0 * BT + bt) * 4 + t];
        id[t] = idxsel[((size_t)1 * BT + bt) * 4 + t];
    }
    __syncthreads();

    const float* __restrict__ Mbt = M + (size_t)bt * NN * NN * NF;

    float4 acc[4][4];
    #pragma unroll
    for (int i = 0; i < 4; ++i)
        #pragma unroll
        for (int s = 0; s < 4; ++s) acc[i][s] = make_float4(0.f, 0.f, 0.f, 0.f);

    for (int j = 0; j < NN; ++j) {
        float w0 = po[0][j], w1 = po[1][j], w2 = po[2][j], w3 = po[3][j];
        #pragma unroll
        for (int s = 0; s < 4; ++s) {
            float4 mv = *(const float4*)&Mbt[(size_t)j * NFK + (size_t)(t + s * 256) * 4];
            acc[0][s].x += w0 * mv.x; acc[0][s].y += w0 * mv.y; acc[0][s].z += w0 * mv.z; acc[0][s].w += w0 * mv.w;
            acc[1][s].x += w1 * mv.x; acc[1][s].y += w1 * mv.y; acc[1][s].z += w1 * mv.z; acc[1][s].w += w1 * mv.w;
            acc[2][s].x += w2 * mv.x; acc[2][s].y += w2 * mv.y; acc[2][s].z += w2 * mv.z; acc[2][s].w += w2 * mv.w;
            acc[3][s].x += w3 * mv.x; acc[3][s].y += w3 * mv.y; acc[3][s].z += w3 * mv.z; acc[3][s].w += w3 * mv.w;
        }
    }

    #pragma unroll
    for (int i = 0; i < 4; ++i)
        #pragma unroll
        for (int s = 0; s < 4; ++s) {
            int pos4 = t + s * 256;
            int k = pos4 >> 4, l4 = (pos4 & 15) * 4;
            *(float4*)&o1[i][k][l4] = acc[i][s];
        }
    __syncthreads();

    // out2: thread -> (i = t/64, k = t%64), 4 j's each
    {
        int i = t >> 6, k = t & 63;
        float vj[4] = {0.f, 0.f, 0.f, 0.f};
        #pragma unroll
        for (int l4 = 0; l4 < 16; ++l4) {
            float4 ov = *(const float4*)&o1[i][k][l4 * 4];
            #pragma unroll
            for (int j = 0; j < 4; ++j) {
                float4 pv = *(const float4*)&pd[j][l4 * 4];
                vj[j] += ov.x * pv.x + ov.y * pv.y + ov.z * pv.z + ov.w * pv.w;
            }
        }
        size_t base = ((size_t)bt * NN + io[i]) * NN;
        #pragma unroll
        for (int j = 0; j < 4; ++j)
            out[(base + id[j]) * NN + k] = vj[j];
    }
}

// ---------------------------------------------------------------------------
extern "C" void kernel_launch(void* const* d_in, const int* in_sizes, int n_in,
                              void* d_out, int out_size, void* d_ws, size_t ws_size,
                              hipStream_t stream)
{
    const float* M   = (const float*)d_in[0];
    const float* Wo  = (const float*)d_in[1];
    const float* bo  = (const float*)d_in[2];
    const float* Wso = (const float*)d_in[3];
    const float* bso = (const float*)d_in[4];
    const float* Wd  = (const float*)d_in[5];
    const float* bd  = (const float*)d_in[6];
    const float* Wsd = (const float*)d_in[7];
    const float* bsd = (const float*)d_in[8];
    float* out = (float*)d_out;

    float* ws   = (float*)d_ws;
    float* weff = ws + WEFF_OFF;
    float* beff = ws + BEFF_OFF;
    float* psel = ws + PSEL_OFF;
    int*   idxs = (int*)(ws + IDX_OFF);

    // output is 99.6% zeros: zero-fill, then scatter only nonzero rows
    hipMemsetAsync(d_out, 0, (size_t)out_size * sizeof(float), stream);

    fold_kernel<<<dim3(64, 2), 256, 0, stream>>>(Wso, Wo, Wsd, Wd, weff);
    bias_kernel<<<1, 128, 0, stream>>>(Wso, bo, bso, Wsd, bd, bsd, beff);
    scores_kernel<<<dim3(BT, 2), 256, 0, stream>>>(M, weff, beff, psel, idxs);
    scatter_kernel<<<BT, 256, 0, stream>>>(M, psel, idxs, out);
}

// Round 2
// 444.146 us; speedup vs baseline: 1.3571x; 1.3571x over previous
//
#include <hip/hip_runtime.h>
#include <math.h>

// Problem constants
#define NB 8
#define NT 16
#define NN 64
#define NF 64
#define NH 1024
#define BT 128          // NB*NT
#define NFK 4096        // NN*NF (K dim of folded score GEMM)

typedef float  f32x4 __attribute__((ext_vector_type(4)));
typedef short  s16x8 __attribute__((ext_vector_type(8)));

#define MFMA_B16(a, b, c) __builtin_amdgcn_mfma_f32_16x16x32_bf16(a, b, c, 0, 0, 0)

// ws layout:
//   wfrag : ushort[2 which][2 part][4 ct][128 ks][64 lane][8 j]  = 2 MB
//   beff  : float[128]
//   psel  : float[2*128*4*64]
//   idxs  : int[2*128*4]
#define WFRAG_USHORTS 1048576
#define BEFF_FOFF     524288
#define PSEL_FOFF     524416
#define IDX_FOFF      589952

__device__ __forceinline__ void split_bf16(float v, unsigned short& hi, unsigned short& lo) {
    unsigned u = __float_as_uint(v);
    float r = v - __uint_as_float(u & 0xFFFF0000u);
    hi = (unsigned short)(u >> 16);
    lo = (unsigned short)(__float_as_uint(r) >> 16);
}

__device__ __forceinline__ void split8(const float4& a0, const float4& a1, s16x8& ah, s16x8& al) {
    float fa[8];
    *(float4*)&fa[0] = a0; *(float4*)&fa[4] = a1;
    #pragma unroll
    for (int j = 0; j < 8; ++j) {
        unsigned u = __float_as_uint(fa[j]);
        float r = fa[j] - __uint_as_float(u & 0xFFFF0000u);
        ah[j] = (short)(u >> 16);
        al[j] = (short)(__float_as_uint(r) >> 16);
    }
}

// ---------------------------------------------------------------------------
// K1: fold W_eff[which] (64x4096) = Wscore(64x1024) @ Wproj(1024x4096),
// epilogue splits to bf16 hi/lo and writes MFMA B-fragment layout.
// grid (64 col-tiles, 2 which), 256 threads
// ---------------------------------------------------------------------------
__global__ __launch_bounds__(256) void fold_kernel(
    const float* __restrict__ Wso, const float* __restrict__ Wo,
    const float* __restrict__ Wsd, const float* __restrict__ Wd,
    unsigned short* __restrict__ wfrag)
{
    const int which = blockIdx.y;
    const float* __restrict__ A  = which ? Wsd : Wso;   // 64 x 1024
    const float* __restrict__ Bm = which ? Wd  : Wo;    // 1024 x 4096
    const int c0 = blockIdx.x * 64;

    __shared__ float As[64][68];   // [row r][h']
    __shared__ float Bs[64][68];   // [col c][h']  (transposed store)

    const int t  = threadIdx.x;
    const int tx = t & 15, ty = t >> 4;

    float acc[4][4] = {};

    for (int h0 = 0; h0 < NH; h0 += 64) {
        #pragma unroll
        for (int it = 0; it < 4; ++it) {
            int r = (t >> 4) + it * 16, c4 = (t & 15) * 4;
            *(float4*)&As[r][c4] = *(const float4*)&A[r * NH + h0 + c4];
        }
        #pragma unroll
        for (int it = 0; it < 4; ++it) {
            int h = (t >> 4) + it * 16, c4 = (t & 15) * 4;
            float4 v = *(const float4*)&Bm[(size_t)(h0 + h) * NFK + c0 + c4];
            Bs[c4 + 0][h] = v.x; Bs[c4 + 1][h] = v.y;
            Bs[c4 + 2][h] = v.z; Bs[c4 + 3][h] = v.w;
        }
        __syncthreads();
        #pragma unroll 4
        for (int kk = 0; kk < 64; kk += 4) {
            float4 a4[4], b4[4];
            #pragma unroll
            for (int m = 0; m < 4; ++m) a4[m] = *(const float4*)&As[ty + 16 * m][kk];
            #pragma unroll
            for (int n = 0; n < 4; ++n) b4[n] = *(const float4*)&Bs[tx + 16 * n][kk];
            #pragma unroll
            for (int m = 0; m < 4; ++m)
                #pragma unroll
                for (int n = 0; n < 4; ++n)
                    acc[m][n] += a4[m].x * b4[n].x + a4[m].y * b4[n].y
                               + a4[m].z * b4[n].z + a4[m].w * b4[n].w;
        }
        __syncthreads();
    }
    // epilogue: split & scatter into B-fragment layout
    // element (r = weff row / N-dim, c = K-dim):
    //   ct = r>>4, lane = ((c>>3)&3)*16 + (r&15), ks = c>>5, j = c&7
    #pragma unroll
    for (int m = 0; m < 4; ++m)
        #pragma unroll
        for (int n = 0; n < 4; ++n) {
            int r = ty + 16 * m;
            int c = c0 + tx + 16 * n;
            unsigned short hi, lo;
            split_bf16(acc[m][n], hi, lo);
            int ct = r >> 4, lane = (((c >> 3) & 3) << 4) | (r & 15);
            int ks = c >> 5, j = c & 7;
            size_t offh = ((((size_t)(which * 2 + 0) * 4 + ct) * 128 + ks) * 64 + lane) * 8 + j;
            size_t offl = ((((size_t)(which * 2 + 1) * 4 + ct) * 128 + ks) * 64 + lane) * 8 + j;
            wfrag[offh] = hi;
            wfrag[offl] = lo;
        }
}

// ---------------------------------------------------------------------------
// K1b: beff[which][r] = Wscore[r,:]·bproj + bscore[r].  grid(2), 256 thr
// ---------------------------------------------------------------------------
__global__ __launch_bounds__(256) void bias_kernel(
    const float* __restrict__ Wso, const float* __restrict__ bo, const float* __restrict__ bso,
    const float* __restrict__ Wsd, const float* __restrict__ bd, const float* __restrict__ bsd,
    float* __restrict__ beff)
{
    const int which = blockIdx.x;
    const float* __restrict__ Ws = which ? Wsd : Wso;
    const float* __restrict__ bb = which ? bd  : bo;
    const float* __restrict__ bs = which ? bsd : bso;
    const int t = threadIdx.x;
    const int r = t >> 2, c = t & 3;
    const float* wp = Ws + r * NH + c * 256;
    const float* bp = bb + c * 256;
    float s = 0.f;
    #pragma unroll 4
    for (int i = 0; i < 64; ++i) {
        float4 wv = *(const float4*)(wp + 4 * i);
        float4 bv = *(const float4*)(bp + 4 * i);
        s += wv.x * bv.x + wv.y * bv.y + wv.z * bv.z + wv.w * bv.w;
    }
    __shared__ float part[64][4];
    part[r][c] = s;
    __syncthreads();
    if (t < 64)
        beff[which * 64 + t] = bs[t] + part[t][0] + part[t][1] + part[t][2] + part[t][3];
}

// ---------------------------------------------------------------------------
// K2: per (bt, which): scores(64x64) = View(M) @ Weff^T + beff via split-bf16
// MFMA (hh + lh + hl), then in-register softmax/entropy, top-4 rows.
// grid (128, 2), 256 threads (4 waves, wave w owns rows 16w..16w+15).
// A-frag: lane l row = 16w + (l&15), k = ks*32 + (l>>4)*8 + j  (direct global)
// B-frag: precomputed wfrag, lane-contiguous 16B loads.
// C-frag: col = 16ct + (l&15), row = 16w + (l>>4)*4 + reg.
// ---------------------------------------------------------------------------
__global__ __launch_bounds__(256) void scores_mfma(
    const float* __restrict__ M, const unsigned short* __restrict__ wfrag,
    const float* __restrict__ beff,
    float* __restrict__ psel, int* __restrict__ idxsel)
{
    const int bt = blockIdx.x, which = blockIdx.y;
    const float* __restrict__ Mbt = M + (size_t)bt * NN * NN * NF;
    const int t = threadIdx.x;
    const int w = t >> 6, l = t & 63, q = l >> 4, ln = l & 15;
    const int arow = 16 * w + ln;

    const unsigned short* __restrict__ wfl = wfrag + (size_t)which * WFRAG_USHORTS / 2 + (size_t)l * 8;
    // B-frag offset for (part, ct, ks): ((part*4+ct)*128 + ks)*512
#define BOFF(part, ct, ks) ((((part) * 4 + (ct)) * 128 + (ks)) * 512)

    // A address: which==0: arow*4096 + ks*32 + q*8
    //            which==1: (ks>>1)*4096 + arow*64 + (ks&1)*32 + q*8
#define AADDR(ks) (Mbt + q * 8 + ((which == 0) \
        ? (arow * NFK + (ks) * 32) \
        : ((((ks) >> 1) * NFK) + arow * 64 + (((ks) & 1) * 32))))

    f32x4 acc[4];
    #pragma unroll
    for (int ct = 0; ct < 4; ++ct) acc[ct] = (f32x4)0.f;

    // 4-kstep A groups (prefetch one group ahead); B double-buffered 1 kstep.
    float4 Ac[4][2], An[4][2];
    #pragma unroll
    for (int kk = 0; kk < 4; ++kk) {
        const float* ap = AADDR(kk);
        Ac[kk][0] = *(const float4*)ap;
        Ac[kk][1] = *(const float4*)(ap + 4);
    }
    s16x8 bhc[4], blc[4];
    #pragma unroll
    for (int ct = 0; ct < 4; ++ct) {
        bhc[ct] = *(const s16x8*)(wfl + BOFF(0, ct, 0));
        blc[ct] = *(const s16x8*)(wfl + BOFF(1, ct, 0));
    }

    for (int g = 0; g < 32; ++g) {
        if (g + 1 < 32) {
            #pragma unroll
            for (int kk = 0; kk < 4; ++kk) {
                const float* ap = AADDR(4 * (g + 1) + kk);
                An[kk][0] = *(const float4*)ap;
                An[kk][1] = *(const float4*)(ap + 4);
            }
        }
        #pragma unroll
        for (int kk = 0; kk < 4; ++kk) {
            const int ks = 4 * g + kk;
            s16x8 bhn[4], bln[4];
            if (ks + 1 < 128) {
                #pragma unroll
                for (int ct = 0; ct < 4; ++ct) {
                    bhn[ct] = *(const s16x8*)(wfl + BOFF(0, ct, ks + 1));
                    bln[ct] = *(const s16x8*)(wfl + BOFF(1, ct, ks + 1));
                }
            }
            s16x8 ah, al;
            split8(Ac[kk][0], Ac[kk][1], ah, al);
            #pragma unroll
            for (int ct = 0; ct < 4; ++ct) {
                acc[ct] = MFMA_B16(ah, bhc[ct], acc[ct]);
                acc[ct] = MFMA_B16(al, bhc[ct], acc[ct]);
                acc[ct] = MFMA_B16(ah, blc[ct], acc[ct]);
            }
            if (ks + 1 < 128) {
                #pragma unroll
                for (int ct = 0; ct < 4; ++ct) { bhc[ct] = bhn[ct]; blc[ct] = bln[ct]; }
            }
        }
        #pragma unroll
        for (int kk = 0; kk < 4; ++kk) { Ac[kk][0] = An[kk][0]; Ac[kk][1] = An[kk][1]; }
    }
#undef AADDR
#undef BOFF

    // bias (per col = 16ct + ln)
    float bv[4];
    #pragma unroll
    for (int ct = 0; ct < 4; ++ct) bv[ct] = beff[which * 64 + 16 * ct + ln];

    // softmax + entropy, rows live across the 16-lane group (l>>4 == q fixed):
    // row = 16w + 4q + reg; cols: lane ln holds {16ct + ln}.
    float p[4][4];   // [ct][reg]
    float H[4];
    #pragma unroll
    for (int reg = 0; reg < 4; ++reg) {
        float s0 = acc[0][reg] + bv[0], s1 = acc[1][reg] + bv[1];
        float s2 = acc[2][reg] + bv[2], s3 = acc[3][reg] + bv[3];
        float m = fmaxf(fmaxf(s0, s1), fmaxf(s2, s3));
        #pragma unroll
        for (int msk = 1; msk < 16; msk <<= 1) m = fmaxf(m, __shfl_xor(m, msk));
        float e0 = expf(s0 - m), e1 = expf(s1 - m), e2 = expf(s2 - m), e3 = expf(s3 - m);
        float sum = e0 + e1 + e2 + e3;
        #pragma unroll
        for (int msk = 1; msk < 16; msk <<= 1) sum += __shfl_xor(sum, msk);
        float inv = 1.0f / sum;
        float pp0 = e0 * inv, pp1 = e1 * inv, pp2 = e2 * inv, pp3 = e3 * inv;
        p[0][reg] = pp0; p[1][reg] = pp1; p[2][reg] = pp2; p[3][reg] = pp3;
        float h = pp0 * logf(pp0 + 1e-9f) + pp1 * logf(pp1 + 1e-9f)
                + pp2 * logf(pp2 + 1e-9f) + pp3 * logf(pp3 + 1e-9f);
        #pragma unroll
        for (int msk = 1; msk < 16; msk <<= 1) h += __shfl_xor(h, msk);
        H[reg] = -h;
    }

    __shared__ float ent[64];
    __shared__ int sel[4];
    if (ln == 0) {
        #pragma unroll
        for (int reg = 0; reg < 4; ++reg) ent[16 * w + 4 * q + reg] = H[reg];
    }
    __syncthreads();
    if (t == 0) {
        unsigned long long used = 0ull;
        for (int s = 0; s < 4; ++s) {
            float best = INFINITY; int bi = 0;
            for (int r = 0; r < 64; ++r) {
                if ((used >> r) & 1ull) continue;
                if (ent[r] < best) { best = ent[r]; bi = r; }
            }
            used |= 1ull << bi;
            sel[s] = bi;
        }
    }
    __syncthreads();
    if (t < 4) idxsel[((size_t)which * BT + bt) * 4 + t] = sel[t];
    #pragma unroll
    for (int s = 0; s < 4; ++s) {
        int row = sel[s];
        if (w == (row >> 4) && q == ((row >> 2) & 3)) {
            int reg = row & 3;
            #pragma unroll
            for (int ct = 0; ct < 4; ++ct)
                psel[(((size_t)which * BT + bt) * 4 + s) * 64 + 16 * ct + ln] = p[ct][reg];
        }
    }
}

// ---------------------------------------------------------------------------
// K3: per (bt, k-slice): out1[i,k,l] = sum_j po[i,j] M[bt,j,k,l] (4 sel i),
// out2 res[i][j][k] = sum_l out1 · pd[j,l]; then write the FULL 256KB output
// slice (zeros + patched res) — no separate memset needed.
// grid (128, 4), 256 threads.
// ---------------------------------------------------------------------------
__global__ __launch_bounds__(256) void scatter_kernel(
    const float* __restrict__ M, const float* __restrict__ psel,
    const int* __restrict__ idxsel, float* __restrict__ out)
{
    const int bt = blockIdx.x, kc = blockIdx.y;     // kc: 16-row k slice
    __shared__ float po[4][64], pd[4][64];
    __shared__ int io[4], id[4];
    __shared__ int rio[64], rid[64];
    __shared__ float o1[4][16][68];
    __shared__ float res[4][4][16];

    const int t = threadIdx.x;
    {
        int s = t >> 6, l = t & 63;
        po[s][l] = psel[(((size_t)0 * BT + bt) * 4 + s) * 64 + l];
        pd[s][l] = psel[(((size_t)1 * BT + bt) * 4 + s) * 64 + l];
    }
    if (t < 64) { rio[t] = -1; rid[t] = -1; }
    if (t >= 64 && t < 68) {
        int s = t - 64;
        io[s] = idxsel[((size_t)0 * BT + bt) * 4 + s];
        id[s] = idxsel[((size_t)1 * BT + bt) * 4 + s];
    }
    __syncthreads();
    if (t < 4) { rio[io[t]] = t; rid[id[t]] = t; }

    const float* __restrict__ Ms = M + (size_t)bt * NN * NFK + kc * 1024 + t * 4;

    float4 a0 = {0,0,0,0}, a1 = {0,0,0,0}, a2 = {0,0,0,0}, a3 = {0,0,0,0};
    #pragma unroll 4
    for (int j = 0; j < NN; ++j) {
        float4 mv = *(const float4*)(Ms + (size_t)j * NFK);
        float w0 = po[0][j], w1 = po[1][j], w2 = po[2][j], w3 = po[3][j];
        a0.x += w0 * mv.x; a0.y += w0 * mv.y; a0.z += w0 * mv.z; a0.w += w0 * mv.w;
        a1.x += w1 * mv.x; a1.y += w1 * mv.y; a1.z += w1 * mv.z; a1.w += w1 * mv.w;
        a2.x += w2 * mv.x; a2.y += w2 * mv.y; a2.z += w2 * mv.z; a2.w += w2 * mv.w;
        a3.x += w3 * mv.x; a3.y += w3 * mv.y; a3.z += w3 * mv.z; a3.w += w3 * mv.w;
    }
    {
        int kl = t >> 4, l4 = (t & 15) * 4;
        *(float4*)&o1[0][kl][l4] = a0;
        *(float4*)&o1[1][kl][l4] = a1;
        *(float4*)&o1[2][kl][l4] = a2;
        *(float4*)&o1[3][kl][l4] = a3;
    }
    __syncthreads();
    {
        int i = t >> 6, jj = (t >> 4) & 3, k = t & 15;
        float v = 0.f;
        #pragma unroll
        for (int l4 = 0; l4 < 16; ++l4) {
            float4 ov = *(const float4*)&o1[i][k][l4 * 4];
            float4 pv = *(const float4*)&pd[jj][l4 * 4];
            v += ov.x * pv.x + ov.y * pv.y + ov.z * pv.z + ov.w * pv.w;
        }
        res[i][jj][k] = v;
    }
    __syncthreads();

    // full-slice write: out[((bt*64+i)*64+jj)*64 + kc*16 + k], k=0..15
    float* __restrict__ obase = out + (size_t)bt * NN * NN * NN + kc * 16;
    #pragma unroll 4
    for (int c = 0; c < 16; ++c) {
        int pos = t + 256 * c;              // (i,jj) pair index
        int i = pos >> 6, jj = pos & 63;
        int ii = rio[i], jd = rid[jj];
        float* dst = obase + (size_t)pos * 64;
        if (ii >= 0 && jd >= 0) {
            *(float4*)(dst + 0)  = *(const float4*)&res[ii][jd][0];
            *(float4*)(dst + 4)  = *(const float4*)&res[ii][jd][4];
            *(float4*)(dst + 8)  = *(const float4*)&res[ii][jd][8];
            *(float4*)(dst + 12) = *(const float4*)&res[ii][jd][12];
        } else {
            float4 z = {0,0,0,0};
            *(float4*)(dst + 0)  = z;
            *(float4*)(dst + 4)  = z;
            *(float4*)(dst + 8)  = z;
            *(float4*)(dst + 12) = z;
        }
    }
}

// ---------------------------------------------------------------------------
extern "C" void kernel_launch(void* const* d_in, const int* in_sizes, int n_in,
                              void* d_out, int out_size, void* d_ws, size_t ws_size,
                              hipStream_t stream)
{
    const float* M   = (const float*)d_in[0];
    const float* Wo  = (const float*)d_in[1];
    const float* bo  = (const float*)d_in[2];
    const float* Wso = (const float*)d_in[3];
    const float* bso = (const float*)d_in[4];
    const float* Wd  = (const float*)d_in[5];
    const float* bd  = (const float*)d_in[6];
    const float* Wsd = (const float*)d_in[7];
    const float* bsd = (const float*)d_in[8];
    float* out = (float*)d_out;

    unsigned short* wfrag = (unsigned short*)d_ws;
    float* beff = (float*)d_ws + BEFF_FOFF;
    float* psel = (float*)d_ws + PSEL_FOFF;
    int*   idxs = (int*)((float*)d_ws + IDX_FOFF);

    fold_kernel<<<dim3(64, 2), 256, 0, stream>>>(Wso, Wo, Wsd, Wd, wfrag);
    bias_kernel<<<2, 256, 0, stream>>>(Wso, bo, bso, Wsd, bd, bsd, beff);
    scores_mfma<<<dim3(BT, 2), 256, 0, stream>>>(M, wfrag, beff, psel, idxs);
    scatter_kernel<<<dim3(BT, 4), 256, 0, stream>>>(M, psel, idxs, out);
}

// Round 4
// 405.721 us; speedup vs baseline: 1.4857x; 1.0947x over previous
//
#include <hip/hip_runtime.h>
#include <math.h>

// Problem constants
#define NB 8
#define NT 16
#define NN 64
#define NF 64
#define NH 1024
#define BT 128          // NB*NT
#define NFK 4096        // NN*NF

typedef float  f32x4 __attribute__((ext_vector_type(4)));
typedef short  s16x8 __attribute__((ext_vector_type(8)));

#define MFMA_B16(a, b, c) __builtin_amdgcn_mfma_f32_16x16x32_bf16(a, b, c, 0, 0, 0)

// ws layout (float offsets); fpart/spart appended dynamically
//   wfrag : ushort[2 which][2 part][4 ct][128 ks][64 lane][8 j] = 2 MB
#define BEFF_FOFF   524288
#define PSEL_FOFF   524416
#define RTAB_FOFF   589952    // int[2][128][64]
#define RES_FOFF    606336    // float[128][4][4][64]
#define DYN_FOFF    737408

__device__ __forceinline__ void split_bf16(float v, unsigned short& hi, unsigned short& lo) {
    unsigned u = __float_as_uint(v);
    float r = v - __uint_as_float(u & 0xFFFF0000u);
    hi = (unsigned short)(u >> 16);
    lo = (unsigned short)(__float_as_uint(r) >> 16);
}

__device__ __forceinline__ void split8(const float4& a0, const float4& a1, s16x8& ah, s16x8& al) {
    float fa[8];
    *(float4*)&fa[0] = a0; *(float4*)&fa[4] = a1;
    #pragma unroll
    for (int j = 0; j < 8; ++j) {
        unsigned u = __float_as_uint(fa[j]);
        float r = fa[j] - __uint_as_float(u & 0xFFFF0000u);
        ah[j] = (short)(u >> 16);
        al[j] = (short)(__float_as_uint(r) >> 16);
    }
}

// ---------------------------------------------------------------------------
// K1a: fold partial: fpart[kc][which][64][4096] += Wscore @ Wproj over h-chunk
// grid (128 col-tiles of 32, 2 which, FCC), 256 threads
// ---------------------------------------------------------------------------
__global__ __launch_bounds__(256) void fold_part(
    const float* __restrict__ Wso, const float* __restrict__ Wo,
    const float* __restrict__ Wsd, const float* __restrict__ Wd,
    float* __restrict__ fpart, int hchunk)
{
    const int which = blockIdx.y, kc = blockIdx.z;
    const float* __restrict__ A  = which ? Wsd : Wso;   // 64 x 1024
    const float* __restrict__ Bm = which ? Wd  : Wo;    // 1024 x 4096
    const int c0 = blockIdx.x * 32;

    __shared__ float As[64][68];
    __shared__ float Bs[32][68];

    const int t = threadIdx.x;
    const int tx = t & 7, ty = t >> 3;   // ty 0..31

    float acc[2][4] = {};

    const int h0beg = kc * hchunk, h0end = h0beg + hchunk;
    for (int h0 = h0beg; h0 < h0end; h0 += 64) {
        #pragma unroll
        for (int it = 0; it < 4; ++it) {
            int r = (t >> 4) + it * 16, c4 = (t & 15) * 4;
            *(float4*)&As[r][c4] = *(const float4*)&A[r * NH + h0 + c4];
        }
        #pragma unroll
        for (int it = 0; it < 2; ++it) {
            int h = (t >> 3) + it * 32, cq = t & 7;
            float4 v = *(const float4*)&Bm[(size_t)(h0 + h) * NFK + c0 + cq * 4];
            Bs[cq * 4 + 0][h] = v.x; Bs[cq * 4 + 1][h] = v.y;
            Bs[cq * 4 + 2][h] = v.z; Bs[cq * 4 + 3][h] = v.w;
        }
        __syncthreads();
        #pragma unroll 4
        for (int kk = 0; kk < 64; kk += 4) {
            float4 a4[2], b4[4];
            a4[0] = *(const float4*)&As[ty][kk];
            a4[1] = *(const float4*)&As[ty + 32][kk];
            #pragma unroll
            for (int n = 0; n < 4; ++n) b4[n] = *(const float4*)&Bs[tx + 8 * n][kk];
            #pragma unroll
            for (int m = 0; m < 2; ++m)
                #pragma unroll
                for (int n = 0; n < 4; ++n)
                    acc[m][n] += a4[m].x * b4[n].x + a4[m].y * b4[n].y
                               + a4[m].z * b4[n].z + a4[m].w * b4[n].w;
        }
        __syncthreads();
    }
    float* __restrict__ outp = fpart + ((size_t)(kc * 2 + which) * 64) * NFK;
    #pragma unroll
    for (int m = 0; m < 2; ++m)
        #pragma unroll
        for (int n = 0; n < 4; ++n)
            outp[(size_t)(ty + 32 * m) * NFK + c0 + tx + 8 * n] = acc[m][n];
}

// ---------------------------------------------------------------------------
// K1b: reduce fold partials, split to bf16 hi/lo, scatter B-fragment layout.
// grid (64 col-tiles of 64, 2 which), 256 threads
// ---------------------------------------------------------------------------
__global__ __launch_bounds__(256) void fold_reduce(
    const float* __restrict__ fpart, unsigned short* __restrict__ wfrag, int fcc)
{
    const int which = blockIdx.y;
    const int c0 = blockIdx.x * 64;
    const int t = threadIdx.x;
    const int r = t >> 2, cb = (t & 3) * 16;

    float s[16] = {};
    for (int c = 0; c < fcc; ++c) {
        const float* __restrict__ p =
            fpart + ((size_t)(c * 2 + which) * 64 + r) * NFK + c0 + cb;
        #pragma unroll
        for (int qq = 0; qq < 4; ++qq) {
            float4 v = *(const float4*)(p + 4 * qq);
            s[4 * qq + 0] += v.x; s[4 * qq + 1] += v.y;
            s[4 * qq + 2] += v.z; s[4 * qq + 3] += v.w;
        }
    }
    #pragma unroll
    for (int jj = 0; jj < 16; ++jj) {
        int c = c0 + cb + jj;
        unsigned short hi, lo;
        split_bf16(s[jj], hi, lo);
        int ct = r >> 4, lane = (((c >> 3) & 3) << 4) | (r & 15);
        int ks = c >> 5, j = c & 7;
        size_t offh = ((((size_t)(which * 2 + 0) * 4 + ct) * 128 + ks) * 64 + lane) * 8 + j;
        size_t offl = ((((size_t)(which * 2 + 1) * 4 + ct) * 128 + ks) * 64 + lane) * 8 + j;
        wfrag[offh] = hi;
        wfrag[offl] = lo;
    }
}

// ---------------------------------------------------------------------------
// K1c: beff[which][r] = Wscore[r,:]·bproj + bscore[r].  grid(2), 256 thr
// ---------------------------------------------------------------------------
__global__ __launch_bounds__(256) void bias_kernel(
    const float* __restrict__ Wso, const float* __restrict__ bo, const float* __restrict__ bso,
    const float* __restrict__ Wsd, const float* __restrict__ bd, const float* __restrict__ bsd,
    float* __restrict__ beff)
{
    const int which = blockIdx.x;
    const float* __restrict__ Ws = which ? Wsd : Wso;
    const float* __restrict__ bb = which ? bd  : bo;
    const float* __restrict__ bs = which ? bsd : bso;
    const int t = threadIdx.x;
    const int r = t >> 2, c = t & 3;
    const float* wp = Ws + r * NH + c * 256;
    const float* bp = bb + c * 256;
    float s = 0.f;
    #pragma unroll 4
    for (int i = 0; i < 64; ++i) {
        float4 wv = *(const float4*)(wp + 4 * i);
        float4 bv = *(const float4*)(bp + 4 * i);
        s += wv.x * bv.x + wv.y * bv.y + wv.z * bv.z + wv.w * bv.w;
    }
    __shared__ float part[64][4];
    part[r][c] = s;
    __syncthreads();
    if (t < 64)
        beff[which * 64 + t] = bs[t] + part[t][0] + part[t][1] + part[t][2] + part[t][3];
}

// ---------------------------------------------------------------------------
// K2a: partial scores GEMM over a K-chunk via split-bf16 MFMA.
// grid (128 bt, 2 which, SCC), 256 threads (4 waves).
// spart[kc][which][bt][row*64+col] fp32.
// ---------------------------------------------------------------------------
__global__ __launch_bounds__(256) void scores_part(
    const float* __restrict__ M, const unsigned short* __restrict__ wfrag,
    float* __restrict__ spart, int ksc)
{
    const int bt = blockIdx.x, which = blockIdx.y, kc = blockIdx.z;
    const float* __restrict__ Mbt = M + (size_t)bt * NN * NN * NF;
    const int t = threadIdx.x;
    const int w = t >> 6, l = t & 63, q = l >> 4, ln = l & 15;
    const int arow = 16 * w + ln;

    const unsigned short* __restrict__ wfl = wfrag + (size_t)which * 524288 + (size_t)l * 8;
#define BOFF(part, ct, ks) ((((part) * 4 + (ct)) * 128 + (ks)) * 512)
#define AADDR(ks) (Mbt + q * 8 + ((which == 0) \
        ? (arow * NFK + (ks) * 32) \
        : ((((ks) >> 1) * NFK) + arow * 64 + (((ks) & 1) * 32))))

    const int ks0 = kc * ksc, ksend = ks0 + ksc;
    const int g0 = ks0 >> 2, gend = ksend >> 2;

    f32x4 acc[4];
    #pragma unroll
    for (int ct = 0; ct < 4; ++ct) acc[ct] = (f32x4)0.f;

    float4 Ac[4][2], An[4][2];
    #pragma unroll
    for (int kk = 0; kk < 4; ++kk) {
        const float* ap = AADDR(ks0 + kk);
        Ac[kk][0] = *(const float4*)ap;
        Ac[kk][1] = *(const float4*)(ap + 4);
    }
    s16x8 bhc[4], blc[4];
    #pragma unroll
    for (int ct = 0; ct < 4; ++ct) {
        bhc[ct] = *(const s16x8*)(wfl + BOFF(0, ct, ks0));
        blc[ct] = *(const s16x8*)(wfl + BOFF(1, ct, ks0));
    }

    for (int g = g0; g < gend; ++g) {
        if (g + 1 < gend) {
            #pragma unroll
            for (int kk = 0; kk < 4; ++kk) {
                const float* ap = AADDR(4 * (g + 1) + kk);
                An[kk][0] = *(const float4*)ap;
                An[kk][1] = *(const float4*)(ap + 4);
            }
        }
        #pragma unroll
        for (int kk = 0; kk < 4; ++kk) {
            const int ks = 4 * g + kk;
            s16x8 bhn[4], bln[4];
            const bool pf = (ks + 1 < ksend);
            if (pf) {
                #pragma unroll
                for (int ct = 0; ct < 4; ++ct) {
                    bhn[ct] = *(const s16x8*)(wfl + BOFF(0, ct, ks + 1));
                    bln[ct] = *(const s16x8*)(wfl + BOFF(1, ct, ks + 1));
                }
            }
            s16x8 ah, al;
            split8(Ac[kk][0], Ac[kk][1], ah, al);
            #pragma unroll
            for (int ct = 0; ct < 4; ++ct) {
                acc[ct] = MFMA_B16(ah, bhc[ct], acc[ct]);
                acc[ct] = MFMA_B16(al, bhc[ct], acc[ct]);
                acc[ct] = MFMA_B16(ah, blc[ct], acc[ct]);
            }
            if (pf) {
                #pragma unroll
                for (int ct = 0; ct < 4; ++ct) { bhc[ct] = bhn[ct]; blc[ct] = bln[ct]; }
            }
        }
        #pragma unroll
        for (int kk = 0; kk < 4; ++kk) { Ac[kk][0] = An[kk][0]; Ac[kk][1] = An[kk][1]; }
    }
#undef AADDR
#undef BOFF

    float* __restrict__ pout = spart + ((size_t)(kc * 2 + which) * BT + bt) * 4096;
    #pragma unroll
    for (int ct = 0; ct < 4; ++ct)
        #pragma unroll
        for (int reg = 0; reg < 4; ++reg)
            pout[(16 * w + 4 * q + reg) * 64 + 16 * ct + ln] = acc[ct][reg];
}

// ---------------------------------------------------------------------------
// K2b: sum partials + bias -> softmax -> entropy -> top-4 -> psel + rtab.
// grid (128, 2), 256 threads. Row r handled by 4 threads (16 cols each).
// ---------------------------------------------------------------------------
__global__ __launch_bounds__(256) void finalize_kernel(
    const float* __restrict__ spart, const float* __restrict__ beff,
    float* __restrict__ psel, int* __restrict__ rtab, int scc)
{
    const int bt = blockIdx.x, which = blockIdx.y;
    const int t = threadIdx.x;
    const int row = t >> 2, cb = (t & 3) * 16;

    float s[16] = {};
    for (int c = 0; c < scc; ++c) {
        const float* __restrict__ p =
            spart + ((size_t)(c * 2 + which) * BT + bt) * 4096 + row * 64 + cb;
        #pragma unroll
        for (int qq = 0; qq < 4; ++qq) {
            float4 v = *(const float4*)(p + 4 * qq);
            s[4 * qq + 0] += v.x; s[4 * qq + 1] += v.y;
            s[4 * qq + 2] += v.z; s[4 * qq + 3] += v.w;
        }
    }
    #pragma unroll
    for (int jj = 0; jj < 16; ++jj) s[jj] += beff[which * 64 + cb + jj];

    float m = -INFINITY;
    #pragma unroll
    for (int jj = 0; jj < 16; ++jj) m = fmaxf(m, s[jj]);
    m = fmaxf(m, __shfl_xor(m, 1));
    m = fmaxf(m, __shfl_xor(m, 2));

    float e[16], sum = 0.f;
    #pragma unroll
    for (int jj = 0; jj < 16; ++jj) { e[jj] = expf(s[jj] - m); sum += e[jj]; }
    sum += __shfl_xor(sum, 1);
    sum += __shfl_xor(sum, 2);
    const float inv = 1.0f / sum;

    float pv[16], h = 0.f;
    #pragma unroll
    for (int jj = 0; jj < 16; ++jj) {
        pv[jj] = e[jj] * inv;
        h += pv[jj] * logf(pv[jj] + 1e-9f);
    }
    h += __shfl_xor(h, 1);
    h += __shfl_xor(h, 2);
    const float H = -h;

    __shared__ float ent[64];
    __shared__ int sel[4];
    if ((t & 3) == 0) ent[row] = H;
    __syncthreads();
    if (t == 0) {
        unsigned long long used = 0ull;
        for (int ss = 0; ss < 4; ++ss) {
            float best = INFINITY; int bi = 0;
            for (int r = 0; r < 64; ++r) {
                if ((used >> r) & 1ull) continue;
                if (ent[r] < best) { best = ent[r]; bi = r; }
            }
            used |= 1ull << bi;
            sel[ss] = bi;
        }
    }
    __syncthreads();

    int* __restrict__ rt = rtab + ((size_t)which * BT + bt) * 64;
    if (t < 64) rt[t] = -1;
    __syncthreads();
    if (t < 4) rt[sel[t]] = t;

    #pragma unroll
    for (int ss = 0; ss < 4; ++ss) {
        if (row == sel[ss]) {
            float* __restrict__ dp = psel + (((size_t)which * BT + bt) * 4 + ss) * 64 + cb;
            #pragma unroll
            for (int jj = 0; jj < 16; ++jj) dp[jj] = pv[jj];
        }
    }
}

// ---------------------------------------------------------------------------
// K3a: res[bt][i][j][k] = sum_l (sum_jj po[i,jj] M[bt,jj,k,l]) * pd[j,l]
// grid (128 bt, 4 k-slices of 16 rows), 256 threads.
// Thread t owns float4 at flat offset t*4 within the 16x64 (k,l) slice:
//   kl = t>>4 (0..15), l = (t&15)*4.
// ---------------------------------------------------------------------------
__global__ __launch_bounds__(256) void res_compute(
    const float* __restrict__ M, const float* __restrict__ psel,
    float* __restrict__ resb)
{
    const int bt = blockIdx.x, kc = blockIdx.y;
    __shared__ float po[4][64], pd[4][64];
    __shared__ float o1[4][16][68];

    const int t = threadIdx.x;
    {
        int ss = t >> 6, l = t & 63;
        po[ss][l] = psel[(((size_t)0 * BT + bt) * 4 + ss) * 64 + l];
        pd[ss][l] = psel[(((size_t)1 * BT + bt) * 4 + ss) * 64 + l];
    }
    __syncthreads();

    const float* __restrict__ Ms = M + (size_t)bt * NN * NFK + kc * 1024 + t * 4;

    float4 a0 = {0,0,0,0}, a1 = {0,0,0,0}, a2 = {0,0,0,0}, a3 = {0,0,0,0};
    #pragma unroll 4
    for (int j = 0; j < NN; ++j) {
        float4 mv = *(const float4*)(Ms + (size_t)j * NFK);
        float w0 = po[0][j], w1 = po[1][j], w2 = po[2][j], w3 = po[3][j];
        a0.x += w0 * mv.x; a0.y += w0 * mv.y; a0.z += w0 * mv.z; a0.w += w0 * mv.w;
        a1.x += w1 * mv.x; a1.y += w1 * mv.y; a1.z += w1 * mv.z; a1.w += w1 * mv.w;
        a2.x += w2 * mv.x; a2.y += w2 * mv.y; a2.z += w2 * mv.z; a2.w += w2 * mv.w;
        a3.x += w3 * mv.x; a3.y += w3 * mv.y; a3.z += w3 * mv.z; a3.w += w3 * mv.w;
    }
    {
        int kl = t >> 4, l4 = (t & 15) * 4;
        *(float4*)&o1[0][kl][l4] = a0;
        *(float4*)&o1[1][kl][l4] = a1;
        *(float4*)&o1[2][kl][l4] = a2;
        *(float4*)&o1[3][kl][l4] = a3;
    }
    __syncthreads();
    {
        int i = t >> 6, jj = (t >> 4) & 3, k = t & 15;
        float v = 0.f;
        #pragma unroll
        for (int l4 = 0; l4 < 16; ++l4) {
            float4 ov = *(const float4*)&o1[i][k][l4 * 4];
            float4 pvv = *(const float4*)&pd[jj][l4 * 4];
            v += ov.x * pvv.x + ov.y * pvv.y + ov.z * pvv.z + ov.w * pvv.w;
        }
        resb[(((size_t)bt * 4 + i) * 4 + jj) * 64 + kc * 16 + k] = v;
    }
}

// ---------------------------------------------------------------------------
// K3b: stream the full output. block b -> (bt = b>>6, i = b&63), writes the
// contiguous 16KB tile out[bt, i, :, :] (zeros or res rows).
// ---------------------------------------------------------------------------
__global__ __launch_bounds__(256) void writer_kernel(
    const float* __restrict__ resb, const int* __restrict__ rtab,
    float* __restrict__ out)
{
    const int b = blockIdx.x, bt = b >> 6, i = b & 63;
    const int t = threadIdx.x;
    __shared__ float rl[4][64];

    const int ii = rtab[((size_t)0 * BT + bt) * 64 + i];
    const int jd = rtab[((size_t)1 * BT + bt) * 64 + (t >> 2)];
    if (ii >= 0)
        rl[t >> 6][t & 63] = resb[(((size_t)bt * 4 + ii) * 4 + (t >> 6)) * 64 + (t & 63)];
    __syncthreads();

    float4 v0 = {0,0,0,0}, v1 = {0,0,0,0}, v2 = {0,0,0,0}, v3 = {0,0,0,0};
    if (ii >= 0 && jd >= 0) {
        const int kb = (t & 3) * 16;
        v0 = *(const float4*)&rl[jd][kb + 0];
        v1 = *(const float4*)&rl[jd][kb + 4];
        v2 = *(const float4*)&rl[jd][kb + 8];
        v3 = *(const float4*)&rl[jd][kb + 12];
    }
    float* __restrict__ dst = out + (size_t)b * 4096 + t * 16;
    *(float4*)(dst + 0)  = v0;
    *(float4*)(dst + 4)  = v1;
    *(float4*)(dst + 8)  = v2;
    *(float4*)(dst + 12) = v3;
}

// ---------------------------------------------------------------------------
extern "C" void kernel_launch(void* const* d_in, const int* in_sizes, int n_in,
                              void* d_out, int out_size, void* d_ws, size_t ws_size,
                              hipStream_t stream)
{
    const float* M   = (const float*)d_in[0];
    const float* Wo  = (const float*)d_in[1];
    const float* bo  = (const float*)d_in[2];
    const float* Wso = (const float*)d_in[3];
    const float* bso = (const float*)d_in[4];
    const float* Wd  = (const float*)d_in[5];
    const float* bd  = (const float*)d_in[6];
    const float* Wsd = (const float*)d_in[7];
    const float* bsd = (const float*)d_in[8];
    float* out = (float*)d_out;

    float* ws = (float*)d_ws;
    unsigned short* wfrag = (unsigned short*)d_ws;
    float* beff = ws + BEFF_FOFF;
    float* psel = ws + PSEL_FOFF;
    int*   rtab = (int*)(ws + RTAB_FOFF);
    float* resb = ws + RES_FOFF;

    int FCC = 2, SCC = 4;
    {
        size_t need = ((size_t)DYN_FOFF + (size_t)FCC * 524288 + (size_t)SCC * 1048576) * 4;
        if (ws_size < need) { FCC = 1; SCC = 1; }
    }
    float* fpart = ws + DYN_FOFF;
    float* spart = fpart + (size_t)FCC * 524288;

    fold_part<<<dim3(128, 2, FCC), 256, 0, stream>>>(Wso, Wo, Wsd, Wd, fpart, NH / FCC);
    bias_kernel<<<2, 256, 0, stream>>>(Wso, bo, bso, Wsd, bd, bsd, beff);
    fold_reduce<<<dim3(64, 2), 256, 0, stream>>>(fpart, wfrag, FCC);
    scores_part<<<dim3(BT, 2, SCC), 256, 0, stream>>>(M, wfrag, spart, 128 / SCC);
    finalize_kernel<<<dim3(BT, 2), 256, 0, stream>>>(spart, beff, psel, rtab, SCC);
    res_compute<<<dim3(BT, 4), 256, 0, stream>>>(M, psel, resb);
    writer_kernel<<<BT * 64, 256, 0, stream>>>(resb, rtab, out);
}

// Round 5
// 378.800 us; speedup vs baseline: 1.5913x; 1.0711x over previous
//
#include <hip/hip_runtime.h>
#include <math.h>

// Problem constants
#define NB 8
#define NT 16
#define NN 64
#define NF 64
#define NH 1024
#define BT 128          // NB*NT
#define NFK 4096        // NN*NF

typedef float  f32x4 __attribute__((ext_vector_type(4)));
typedef short  s16x8 __attribute__((ext_vector_type(8)));

#define MFMA_B16(a, b, c) __builtin_amdgcn_mfma_f32_16x16x32_bf16(a, b, c, 0, 0, 0)

// ws layout (float offsets)
//   wfrag : ushort[2 which][2 part][4 ct][128 ks][64 lane][8 j] = 2 MB
#define BEFF_FOFF   524288
#define PSEL_FOFF   524416   // float[2][128][4][64]
#define RTAB_FOFF   589952   // int[2][128][64]
#define RES_FOFF    606336   // float[2 jh][128][4][4][64] = 262144
#define DYN_FOFF    868480

__device__ __forceinline__ void split_bf16(float v, unsigned short& hi, unsigned short& lo) {
    unsigned u = __float_as_uint(v);
    float r = v - __uint_as_float(u & 0xFFFF0000u);
    hi = (unsigned short)(u >> 16);
    lo = (unsigned short)(__float_as_uint(r) >> 16);
}

__device__ __forceinline__ void split8(const float4& a0, const float4& a1, s16x8& ah, s16x8& al) {
    float fa[8];
    *(float4*)&fa[0] = a0; *(float4*)&fa[4] = a1;
    #pragma unroll
    for (int j = 0; j < 8; ++j) {
        unsigned u = __float_as_uint(fa[j]);
        float r = fa[j] - __uint_as_float(u & 0xFFFF0000u);
        ah[j] = (short)(u >> 16);
        al[j] = (short)(__float_as_uint(r) >> 16);
    }
}

// ---------------------------------------------------------------------------
// K1a: fold partial: fpart[kc][which][64][4096] = Wscore @ Wproj over h-chunk
// grid (128 col-tiles of 32, 2 which, FCC), 256 threads
// ---------------------------------------------------------------------------
__global__ __launch_bounds__(256) void fold_part(
    const float* __restrict__ Wso, const float* __restrict__ Wo,
    const float* __restrict__ Wsd, const float* __restrict__ Wd,
    float* __restrict__ fpart, int hchunk)
{
    const int which = blockIdx.y, kc = blockIdx.z;
    const float* __restrict__ A  = which ? Wsd : Wso;   // 64 x 1024
    const float* __restrict__ Bm = which ? Wd  : Wo;    // 1024 x 4096
    const int c0 = blockIdx.x * 32;

    __shared__ float As[64][68];
    __shared__ float Bs[32][68];

    const int t = threadIdx.x;
    const int tx = t & 7, ty = t >> 3;   // ty 0..31

    float acc[2][4] = {};

    const int h0beg = kc * hchunk, h0end = h0beg + hchunk;
    for (int h0 = h0beg; h0 < h0end; h0 += 64) {
        #pragma unroll
        for (int it = 0; it < 4; ++it) {
            int r = (t >> 4) + it * 16, c4 = (t & 15) * 4;
            *(float4*)&As[r][c4] = *(const float4*)&A[r * NH + h0 + c4];
        }
        #pragma unroll
        for (int it = 0; it < 2; ++it) {
            int h = (t >> 3) + it * 32, cq = t & 7;
            float4 v = *(const float4*)&Bm[(size_t)(h0 + h) * NFK + c0 + cq * 4];
            Bs[cq * 4 + 0][h] = v.x; Bs[cq * 4 + 1][h] = v.y;
            Bs[cq * 4 + 2][h] = v.z; Bs[cq * 4 + 3][h] = v.w;
        }
        __syncthreads();
        #pragma unroll 4
        for (int kk = 0; kk < 64; kk += 4) {
            float4 a4[2], b4[4];
            a4[0] = *(const float4*)&As[ty][kk];
            a4[1] = *(const float4*)&As[ty + 32][kk];
            #pragma unroll
            for (int n = 0; n < 4; ++n) b4[n] = *(const float4*)&Bs[tx + 8 * n][kk];
            #pragma unroll
            for (int m = 0; m < 2; ++m)
                #pragma unroll
                for (int n = 0; n < 4; ++n)
                    acc[m][n] += a4[m].x * b4[n].x + a4[m].y * b4[n].y
                               + a4[m].z * b4[n].z + a4[m].w * b4[n].w;
        }
        __syncthreads();
    }
    float* __restrict__ outp = fpart + ((size_t)(kc * 2 + which) * 64) * NFK;
    #pragma unroll
    for (int m = 0; m < 2; ++m)
        #pragma unroll
        for (int n = 0; n < 4; ++n)
            outp[(size_t)(ty + 32 * m) * NFK + c0 + tx + 8 * n] = acc[m][n];
}

// ---------------------------------------------------------------------------
// K1b: reduce fold partials -> bf16 hi/lo B-fragment layout; block x==0 also
// computes beff[which] (fused bias kernel).
// grid (64 col-tiles of 64, 2 which), 256 threads
// ---------------------------------------------------------------------------
__global__ __launch_bounds__(256) void fold_reduce(
    const float* __restrict__ fpart, unsigned short* __restrict__ wfrag, int fcc,
    const float* __restrict__ Wso, const float* __restrict__ bo, const float* __restrict__ bso,
    const float* __restrict__ Wsd, const float* __restrict__ bd, const float* __restrict__ bsd,
    float* __restrict__ beff)
{
    const int which = blockIdx.y;
    const int c0 = blockIdx.x * 64;
    const int t = threadIdx.x;
    const int r = t >> 2, cb = (t & 3) * 16;

    float s[16] = {};
    for (int c = 0; c < fcc; ++c) {
        const float* __restrict__ p =
            fpart + ((size_t)(c * 2 + which) * 64 + r) * NFK + c0 + cb;
        #pragma unroll
        for (int qq = 0; qq < 4; ++qq) {
            float4 v = *(const float4*)(p + 4 * qq);
            s[4 * qq + 0] += v.x; s[4 * qq + 1] += v.y;
            s[4 * qq + 2] += v.z; s[4 * qq + 3] += v.w;
        }
    }
    #pragma unroll
    for (int jj = 0; jj < 16; ++jj) {
        int c = c0 + cb + jj;
        unsigned short hi, lo;
        split_bf16(s[jj], hi, lo);
        int ct = r >> 4, lane = (((c >> 3) & 3) << 4) | (r & 15);
        int ks = c >> 5, j = c & 7;
        size_t offh = ((((size_t)(which * 2 + 0) * 4 + ct) * 128 + ks) * 64 + lane) * 8 + j;
        size_t offl = ((((size_t)(which * 2 + 1) * 4 + ct) * 128 + ks) * 64 + lane) * 8 + j;
        wfrag[offh] = hi;
        wfrag[offl] = lo;
    }

    // fused bias: beff[which][r] = Wscore[r,:]·bproj + bscore[r]
    if (blockIdx.x == 0) {
        const float* __restrict__ Ws = which ? Wsd : Wso;
        const float* __restrict__ bb = which ? bd  : bo;
        const float* __restrict__ bs = which ? bsd : bso;
        const int r2 = t >> 2, c2 = t & 3;
        const float* wp = Ws + r2 * NH + c2 * 256;
        const float* bp = bb + c2 * 256;
        float sacc = 0.f;
        #pragma unroll 4
        for (int i2 = 0; i2 < 64; ++i2) {
            float4 wv = *(const float4*)(wp + 4 * i2);
            float4 bv = *(const float4*)(bp + 4 * i2);
            sacc += wv.x * bv.x + wv.y * bv.y + wv.z * bv.z + wv.w * bv.w;
        }
        __shared__ float part[64][4];
        part[r2][c2] = sacc;
        __syncthreads();
        if (t < 64)
            beff[which * 64 + t] = bs[t] + part[t][0] + part[t][1] + part[t][2] + part[t][3];
    }
}

// ---------------------------------------------------------------------------
// K2a: partial scores GEMM over a K-chunk, split-bf16 MFMA (hh+lh+hl).
// B fragments staged global->reg->LDS (double-buffered, 64 KB) so the
// per-kstep B waits are lgkmcnt (ds_read), decoupled from the A-group
// HBM prefetch in the vmcnt queue. One barrier per 4-kstep group.
// grid (128 bt, 2 which, SCC), 256 threads.
// ---------------------------------------------------------------------------
#define CHUNK(fid, ks) ((size_t)((fid) * 128 + (ks)) * 512)

__global__ __launch_bounds__(256) void scores_part(
    const float* __restrict__ M, const unsigned short* __restrict__ wfrag,
    float* __restrict__ spart, int ksc)
{
    const int bt = blockIdx.x, which = blockIdx.y, kc = blockIdx.z;
    const float* __restrict__ Mbt = M + (size_t)bt * NN * NFK;
    const int t = threadIdx.x;
    const int w = t >> 6, l = t & 63, q = l >> 4, ln = l & 15;
    const int arow = 16 * w + ln;

    __shared__ unsigned short Bsh[2][4][8][512];   // 64 KB: [buf][kk][frag][lane*8+j]

    const unsigned short* __restrict__ wbase = wfrag + (size_t)which * 524288;

#define AADDR(ks) (Mbt + q * 8 + ((which == 0) \
        ? (arow * NFK + (ks) * 32) \
        : ((((ks) >> 1) * NFK) + arow * 64 + (((ks) & 1) * 32))))

    const int ks0 = kc * ksc;
    const int ngroups = ksc >> 2;

    f32x4 acc[4];
    #pragma unroll
    for (int ct = 0; ct < 4; ++ct) acc[ct] = (f32x4)0.f;

    float4 Ac[4][2], An[4][2];
    s16x8 Bn[8];

    // prologue: A group 0 to regs; B group 0 reg-staged into LDS buf 0
    #pragma unroll
    for (int kk = 0; kk < 4; ++kk) {
        const float* ap = AADDR(ks0 + kk);
        Ac[kk][0] = *(const float4*)ap;
        Ac[kk][1] = *(const float4*)(ap + 4);
        #pragma unroll
        for (int ii = 0; ii < 2; ++ii)
            Bn[kk * 2 + ii] = *(const s16x8*)(wbase + CHUNK(w + ii * 4, ks0 + kk) + l * 8);
    }
    #pragma unroll
    for (int kk = 0; kk < 4; ++kk)
        #pragma unroll
        for (int ii = 0; ii < 2; ++ii)
            *(s16x8*)&Bsh[0][kk][w + ii * 4][l * 8] = Bn[kk * 2 + ii];
    __syncthreads();

    int cur = 0;
    for (int g = 0; g < ngroups; ++g) {
        const bool more = (g + 1 < ngroups);
        const int ksn = ks0 + (g + 1) * 4;
        if (more) {
            // issue next-group loads (in flight across this group's compute)
            #pragma unroll
            for (int kk = 0; kk < 4; ++kk) {
                const float* ap = AADDR(ksn + kk);
                An[kk][0] = *(const float4*)ap;
                An[kk][1] = *(const float4*)(ap + 4);
                #pragma unroll
                for (int ii = 0; ii < 2; ++ii)
                    Bn[kk * 2 + ii] = *(const s16x8*)(wbase + CHUNK(w + ii * 4, ksn + kk) + l * 8);
            }
        }
        // compute current group from LDS (lgkmcnt domain only)
        #pragma unroll
        for (int kk = 0; kk < 4; ++kk) {
            s16x8 bh[4], bl[4];
            #pragma unroll
            for (int ct = 0; ct < 4; ++ct) {
                bh[ct] = *(const s16x8*)&Bsh[cur][kk][ct][l * 8];
                bl[ct] = *(const s16x8*)&Bsh[cur][kk][4 + ct][l * 8];
            }
            s16x8 ah, al;
            split8(Ac[kk][0], Ac[kk][1], ah, al);
            #pragma unroll
            for (int ct = 0; ct < 4; ++ct) {
                acc[ct] = MFMA_B16(ah, bh[ct], acc[ct]);
                acc[ct] = MFMA_B16(al, bh[ct], acc[ct]);
                acc[ct] = MFMA_B16(ah, bl[ct], acc[ct]);
            }
        }
        if (more) {
            // drain staged regs into alt LDS buffer; advance A regs
            #pragma unroll
            for (int kk = 0; kk < 4; ++kk)
                #pragma unroll
                for (int ii = 0; ii < 2; ++ii)
                    *(s16x8*)&Bsh[cur ^ 1][kk][w + ii * 4][l * 8] = Bn[kk * 2 + ii];
            #pragma unroll
            for (int kk = 0; kk < 4; ++kk) { Ac[kk][0] = An[kk][0]; Ac[kk][1] = An[kk][1]; }
            __syncthreads();
            cur ^= 1;
        }
    }
#undef AADDR

    float* __restrict__ pout = spart + ((size_t)(kc * 2 + which) * BT + bt) * 4096;
    #pragma unroll
    for (int ct = 0; ct < 4; ++ct)
        #pragma unroll
        for (int reg = 0; reg < 4; ++reg)
            pout[(16 * w + 4 * q + reg) * 64 + 16 * ct + ln] = acc[ct][reg];
}

// ---------------------------------------------------------------------------
// K2b: sum partials + bias -> softmax -> entropy -> top-4 -> psel + rtab.
// grid (128, 2), 256 threads.
// ---------------------------------------------------------------------------
__global__ __launch_bounds__(256) void finalize_kernel(
    const float* __restrict__ spart, const float* __restrict__ beff,
    float* __restrict__ psel, int* __restrict__ rtab, int scc)
{
    const int bt = blockIdx.x, which = blockIdx.y;
    const int t = threadIdx.x;
    const int row = t >> 2, cb = (t & 3) * 16;

    float s[16] = {};
    for (int c = 0; c < scc; ++c) {
        const float* __restrict__ p =
            spart + ((size_t)(c * 2 + which) * BT + bt) * 4096 + row * 64 + cb;
        #pragma unroll
        for (int qq = 0; qq < 4; ++qq) {
            float4 v = *(const float4*)(p + 4 * qq);
            s[4 * qq + 0] += v.x; s[4 * qq + 1] += v.y;
            s[4 * qq + 2] += v.z; s[4 * qq + 3] += v.w;
        }
    }
    #pragma unroll
    for (int jj = 0; jj < 16; ++jj) s[jj] += beff[which * 64 + cb + jj];

    float m = -INFINITY;
    #pragma unroll
    for (int jj = 0; jj < 16; ++jj) m = fmaxf(m, s[jj]);
    m = fmaxf(m, __shfl_xor(m, 1));
    m = fmaxf(m, __shfl_xor(m, 2));

    float e[16], sum = 0.f;
    #pragma unroll
    for (int jj = 0; jj < 16; ++jj) { e[jj] = expf(s[jj] - m); sum += e[jj]; }
    sum += __shfl_xor(sum, 1);
    sum += __shfl_xor(sum, 2);
    const float inv = 1.0f / sum;

    float pv[16], h = 0.f;
    #pragma unroll
    for (int jj = 0; jj < 16; ++jj) {
        pv[jj] = e[jj] * inv;
        h += pv[jj] * logf(pv[jj] + 1e-9f);
    }
    h += __shfl_xor(h, 1);
    h += __shfl_xor(h, 2);
    const float H = -h;

    __shared__ float ent[64];
    __shared__ int sel[4];
    if ((t & 3) == 0) ent[row] = H;
    __syncthreads();
    if (t == 0) {
        unsigned long long used = 0ull;
        for (int ss = 0; ss < 4; ++ss) {
            float best = INFINITY; int bi = 0;
            for (int r = 0; r < 64; ++r) {
                if ((used >> r) & 1ull) continue;
                if (ent[r] < best) { best = ent[r]; bi = r; }
            }
            used |= 1ull << bi;
            sel[ss] = bi;
        }
    }
    __syncthreads();

    int* __restrict__ rt = rtab + ((size_t)which * BT + bt) * 64;
    if (t < 64) rt[t] = -1;
    __syncthreads();
    if (t < 4) rt[sel[t]] = t;

    #pragma unroll
    for (int ss = 0; ss < 4; ++ss) {
        if (row == sel[ss]) {
            float* __restrict__ dp = psel + (((size_t)which * BT + bt) * 4 + ss) * 64 + cb;
            #pragma unroll
            for (int jj = 0; jj < 16; ++jj) dp[jj] = pv[jj];
        }
    }
}

// ---------------------------------------------------------------------------
// K3a: partial over a j-half: res2[jh][bt][i][jj][k] contribution.
// grid (128 bt, 4 k-slices of 16 rows, 2 j-halves), 256 threads.
// ---------------------------------------------------------------------------
__global__ __launch_bounds__(256) void res_compute(
    const float* __restrict__ M, const float* __restrict__ psel,
    float* __restrict__ resb2)
{
    const int bt = blockIdx.x, kc = blockIdx.y, jh = blockIdx.z;
    __shared__ float po[4][64], pd[4][64];
    __shared__ float o1[4][16][68];

    const int t = threadIdx.x;
    {
        int ss = t >> 6, ll = t & 63;
        po[ss][ll] = psel[(((size_t)0 * BT + bt) * 4 + ss) * 64 + ll];
        pd[ss][ll] = psel[(((size_t)1 * BT + bt) * 4 + ss) * 64 + ll];
    }
    __syncthreads();

    const float* __restrict__ Ms =
        M + (size_t)bt * NN * NFK + (size_t)(jh * 32) * NFK + kc * 1024 + t * 4;

    float4 a0 = {0,0,0,0}, a1 = {0,0,0,0}, a2 = {0,0,0,0}, a3 = {0,0,0,0};
    #pragma unroll 8
    for (int j = 0; j < 32; ++j) {
        float4 mv = *(const float4*)(Ms + (size_t)j * NFK);
        int jg = jh * 32 + j;
        float w0 = po[0][jg], w1 = po[1][jg], w2 = po[2][jg], w3 = po[3][jg];
        a0.x += w0 * mv.x; a0.y += w0 * mv.y; a0.z += w0 * mv.z; a0.w += w0 * mv.w;
        a1.x += w1 * mv.x; a1.y += w1 * mv.y; a1.z += w1 * mv.z; a1.w += w1 * mv.w;
        a2.x += w2 * mv.x; a2.y += w2 * mv.y; a2.z += w2 * mv.z; a2.w += w2 * mv.w;
        a3.x += w3 * mv.x; a3.y += w3 * mv.y; a3.z += w3 * mv.z; a3.w += w3 * mv.w;
    }
    {
        int kl = t >> 4, l4 = (t & 15) * 4;
        *(float4*)&o1[0][kl][l4] = a0;
        *(float4*)&o1[1][kl][l4] = a1;
        *(float4*)&o1[2][kl][l4] = a2;
        *(float4*)&o1[3][kl][l4] = a3;
    }
    __syncthreads();
    {
        int i = t >> 6, jj = (t >> 4) & 3, k = t & 15;
        float v = 0.f;
        #pragma unroll
        for (int l4 = 0; l4 < 16; ++l4) {
            float4 ov = *(const float4*)&o1[i][k][l4 * 4];
            float4 pvv = *(const float4*)&pd[jj][l4 * 4];
            v += ov.x * pvv.x + ov.y * pvv.y + ov.z * pvv.z + ov.w * pvv.w;
        }
        resb2[((((size_t)jh * BT + bt) * 4 + i) * 4 + jj) * 64 + kc * 16 + k] = v;
    }
}

// ---------------------------------------------------------------------------
// K3b: stream the full output, unit-stride. block b -> (bt=b>>6, i=b&63),
// writes contiguous 16KB tile out[bt,i,:,:] (zeros or summed res rows).
// ---------------------------------------------------------------------------
__global__ __launch_bounds__(256) void writer_kernel(
    const float* __restrict__ resb2, const int* __restrict__ rtab,
    float* __restrict__ out)
{
    const int b = blockIdx.x, bt = b >> 6, i = b & 63;
    const int t = threadIdx.x;
    __shared__ float rl[4][64];
    __shared__ int jdl[64];

    const int ii = rtab[(size_t)bt * 64 + i];
    if (t < 64) jdl[t] = rtab[(size_t)BT * 64 + (size_t)bt * 64 + t];
    if (ii >= 0) {
        int jj = t >> 6, k = t & 63;
        size_t base = (((size_t)bt * 4 + ii) * 4 + jj) * 64 + k;
        rl[jj][k] = resb2[base] + resb2[(size_t)BT * 4 * 4 * 64 + base];
    }
    __syncthreads();

    float* __restrict__ dst = out + (size_t)b * 4096;
    #pragma unroll
    for (int s = 0; s < 4; ++s) {
        int p = s * 1024 + t * 4;          // unit-stride across the wave
        int jj = p >> 6, k = p & 63;
        float4 v = {0.f, 0.f, 0.f, 0.f};
        if (ii >= 0) {
            int jd = jdl[jj];
            if (jd >= 0) v = *(const float4*)&rl[jd][k];
        }
        *(float4*)(dst + p) = v;
    }
}

// ---------------------------------------------------------------------------
extern "C" void kernel_launch(void* const* d_in, const int* in_sizes, int n_in,
                              void* d_out, int out_size, void* d_ws, size_t ws_size,
                              hipStream_t stream)
{
    const float* M   = (const float*)d_in[0];
    const float* Wo  = (const float*)d_in[1];
    const float* bo  = (const float*)d_in[2];
    const float* Wso = (const float*)d_in[3];
    const float* bso = (const float*)d_in[4];
    const float* Wd  = (const float*)d_in[5];
    const float* bd  = (const float*)d_in[6];
    const float* Wsd = (const float*)d_in[7];
    const float* bsd = (const float*)d_in[8];
    float* out = (float*)d_out;

    float* ws = (float*)d_ws;
    unsigned short* wfrag = (unsigned short*)d_ws;
    float* beff  = ws + BEFF_FOFF;
    float* psel  = ws + PSEL_FOFF;
    int*   rtab  = (int*)(ws + RTAB_FOFF);
    float* resb2 = ws + RES_FOFF;

    int FCC = 2, SCC = 4;
    {
        size_t need = ((size_t)DYN_FOFF + (size_t)FCC * 524288 + (size_t)SCC * 1048576) * 4;
        if (ws_size < need) { FCC = 1; SCC = 1; }
    }
    float* fpart = ws + DYN_FOFF;
    float* spart = fpart + (size_t)FCC * 524288;

    fold_part<<<dim3(128, 2, FCC), 256, 0, stream>>>(Wso, Wo, Wsd, Wd, fpart, NH / FCC);
    fold_reduce<<<dim3(64, 2), 256, 0, stream>>>(fpart, wfrag, FCC,
                                                 Wso, bo, bso, Wsd, bd, bsd, beff);
    scores_part<<<dim3(BT, 2, SCC), 256, 0, stream>>>(M, wfrag, spart, 128 / SCC);
    finalize_kernel<<<dim3(BT, 2), 256, 0, stream>>>(spart, beff, psel, rtab, SCC);
    res_compute<<<dim3(BT, 4, 2), 256, 0, stream>>>(M, psel, resb2);
    writer_kernel<<<BT * 64, 256, 0, stream>>>(resb2, rtab, out);
}

// Round 6
// 375.092 us; speedup vs baseline: 1.6070x; 1.0099x over previous
//
#include <hip/hip_runtime.h>
#include <math.h>

// Problem constants
#define NB 8
#define NT 16
#define NN 64
#define NF 64
#define NH 1024
#define BT 128          // NB*NT
#define NFK 4096        // NN*NF

typedef float  f32x4 __attribute__((ext_vector_type(4)));
typedef short  s16x8 __attribute__((ext_vector_type(8)));

#define MFMA_B16(a, b, c) __builtin_amdgcn_mfma_f32_16x16x32_bf16(a, b, c, 0, 0, 0)

// ws layout (float offsets)
//   wfrag : ushort[2 which][2 part][4 ct][128 ks][64 lane][8 j] = 2 MB
#define BEFF_FOFF   524288
#define PSEL_FOFF   524416   // float[2][128][4][64]
#define RTAB_FOFF   589952   // int[2][128][64]
#define RES_FOFF    606336   // float[JH][128][4][4][64]

__device__ __forceinline__ void split_bf16(float v, unsigned short& hi, unsigned short& lo) {
    unsigned u = __float_as_uint(v);
    float r = v - __uint_as_float(u & 0xFFFF0000u);
    hi = (unsigned short)(u >> 16);
    lo = (unsigned short)(__float_as_uint(r) >> 16);
}

__device__ __forceinline__ void split8(const float4& a0, const float4& a1, s16x8& ah, s16x8& al) {
    float fa[8];
    *(float4*)&fa[0] = a0; *(float4*)&fa[4] = a1;
    #pragma unroll
    for (int j = 0; j < 8; ++j) {
        unsigned u = __float_as_uint(fa[j]);
        float r = fa[j] - __uint_as_float(u & 0xFFFF0000u);
        ah[j] = (short)(u >> 16);
        al[j] = (short)(__float_as_uint(r) >> 16);
    }
}

// ---------------------------------------------------------------------------
// K1a: fold partial: fpart[kc][which][64][4096] = Wscore @ Wproj over h-chunk
// grid (128 col-tiles of 32, 2 which, FCC), 256 threads
// ---------------------------------------------------------------------------
__global__ __launch_bounds__(256) void fold_part(
    const float* __restrict__ Wso, const float* __restrict__ Wo,
    const float* __restrict__ Wsd, const float* __restrict__ Wd,
    float* __restrict__ fpart, int hchunk)
{
    const int which = blockIdx.y, kc = blockIdx.z;
    const float* __restrict__ A  = which ? Wsd : Wso;   // 64 x 1024
    const float* __restrict__ Bm = which ? Wd  : Wo;    // 1024 x 4096
    const int c0 = blockIdx.x * 32;

    __shared__ float As[64][68];
    __shared__ float Bs[32][68];

    const int t = threadIdx.x;
    const int tx = t & 7, ty = t >> 3;   // ty 0..31

    float acc[2][4] = {};

    const int h0beg = kc * hchunk, h0end = h0beg + hchunk;
    for (int h0 = h0beg; h0 < h0end; h0 += 64) {
        #pragma unroll
        for (int it = 0; it < 4; ++it) {
            int r = (t >> 4) + it * 16, c4 = (t & 15) * 4;
            *(float4*)&As[r][c4] = *(const float4*)&A[r * NH + h0 + c4];
        }
        #pragma unroll
        for (int it = 0; it < 2; ++it) {
            int h = (t >> 3) + it * 32, cq = t & 7;
            float4 v = *(const float4*)&Bm[(size_t)(h0 + h) * NFK + c0 + cq * 4];
            Bs[cq * 4 + 0][h] = v.x; Bs[cq * 4 + 1][h] = v.y;
            Bs[cq * 4 + 2][h] = v.z; Bs[cq * 4 + 3][h] = v.w;
        }
        __syncthreads();
        #pragma unroll 4
        for (int kk = 0; kk < 64; kk += 4) {
            float4 a4[2], b4[4];
            a4[0] = *(const float4*)&As[ty][kk];
            a4[1] = *(const float4*)&As[ty + 32][kk];
            #pragma unroll
            for (int n = 0; n < 4; ++n) b4[n] = *(const float4*)&Bs[tx + 8 * n][kk];
            #pragma unroll
            for (int m = 0; m < 2; ++m)
                #pragma unroll
                for (int n = 0; n < 4; ++n)
                    acc[m][n] += a4[m].x * b4[n].x + a4[m].y * b4[n].y
                               + a4[m].z * b4[n].z + a4[m].w * b4[n].w;
        }
        __syncthreads();
    }
    float* __restrict__ outp = fpart + ((size_t)(kc * 2 + which) * 64) * NFK;
    #pragma unroll
    for (int m = 0; m < 2; ++m)
        #pragma unroll
        for (int n = 0; n < 4; ++n)
            outp[(size_t)(ty + 32 * m) * NFK + c0 + tx + 8 * n] = acc[m][n];
}

// ---------------------------------------------------------------------------
// K1b: reduce fold partials -> bf16 hi/lo B-fragment layout; block x==0 also
// computes beff[which] (fused bias kernel).
// grid (64 col-tiles of 64, 2 which), 256 threads
// ---------------------------------------------------------------------------
__global__ __launch_bounds__(256) void fold_reduce(
    const float* __restrict__ fpart, unsigned short* __restrict__ wfrag, int fcc,
    const float* __restrict__ Wso, const float* __restrict__ bo, const float* __restrict__ bso,
    const float* __restrict__ Wsd, const float* __restrict__ bd, const float* __restrict__ bsd,
    float* __restrict__ beff)
{
    const int which = blockIdx.y;
    const int c0 = blockIdx.x * 64;
    const int t = threadIdx.x;
    const int r = t >> 2, cb = (t & 3) * 16;

    float s[16] = {};
    for (int c = 0; c < fcc; ++c) {
        const float* __restrict__ p =
            fpart + ((size_t)(c * 2 + which) * 64 + r) * NFK + c0 + cb;
        #pragma unroll
        for (int qq = 0; qq < 4; ++qq) {
            float4 v = *(const float4*)(p + 4 * qq);
            s[4 * qq + 0] += v.x; s[4 * qq + 1] += v.y;
            s[4 * qq + 2] += v.z; s[4 * qq + 3] += v.w;
        }
    }
    #pragma unroll
    for (int jj = 0; jj < 16; ++jj) {
        int c = c0 + cb + jj;
        unsigned short hi, lo;
        split_bf16(s[jj], hi, lo);
        int ct = r >> 4, lane = (((c >> 3) & 3) << 4) | (r & 15);
        int ks = c >> 5, j = c & 7;
        size_t offh = ((((size_t)(which * 2 + 0) * 4 + ct) * 128 + ks) * 64 + lane) * 8 + j;
        size_t offl = ((((size_t)(which * 2 + 1) * 4 + ct) * 128 + ks) * 64 + lane) * 8 + j;
        wfrag[offh] = hi;
        wfrag[offl] = lo;
    }

    // fused bias: beff[which][r] = Wscore[r,:]·bproj + bscore[r]
    if (blockIdx.x == 0) {
        const float* __restrict__ Ws = which ? Wsd : Wso;
        const float* __restrict__ bb = which ? bd  : bo;
        const float* __restrict__ bs = which ? bsd : bso;
        const int r2 = t >> 2, c2 = t & 3;
        const float* wp = Ws + r2 * NH + c2 * 256;
        const float* bp = bb + c2 * 256;
        float sacc = 0.f;
        #pragma unroll 4
        for (int i2 = 0; i2 < 64; ++i2) {
            float4 wv = *(const float4*)(wp + 4 * i2);
            float4 bv = *(const float4*)(bp + 4 * i2);
            sacc += wv.x * bv.x + wv.y * bv.y + wv.z * bv.z + wv.w * bv.w;
        }
        __shared__ float part[64][4];
        part[r2][c2] = sacc;
        __syncthreads();
        if (t < 64)
            beff[which * 64 + t] = bs[t] + part[t][0] + part[t][1] + part[t][2] + part[t][3];
    }
}

// ---------------------------------------------------------------------------
// K2a: partial scores GEMM over a K-chunk, split-bf16 MFMA (hh+lh+hl).
// 2-kstep groups, SINGLE 16 KB LDS buffer for B (compute -> sync -> write
// next group's B -> sync). B loads issued BEFORE A loads each group so the
// counted vmcnt for the ds_write drains only B, leaving the A prefetch in
// flight. Ping-pong A register sets (no copy-wait). 16 KB LDS + ~105 VGPR
// -> 4 blocks/CU (~50% occupancy) vs round-5's 2.
// grid (128 bt, 2 which, SCC), 256 threads.
// ---------------------------------------------------------------------------
#define CHUNK(fid, ks) ((size_t)((fid) * 128 + (ks)) * 512)

__global__ __launch_bounds__(256) void scores_part(
    const float* __restrict__ M, const unsigned short* __restrict__ wfrag,
    float* __restrict__ spart, int ksc)
{
    const int bt = blockIdx.x, which = blockIdx.y, kc = blockIdx.z;
    const float* __restrict__ Mbt = M + (size_t)bt * NN * NFK;
    const int t = threadIdx.x;
    const int w = t >> 6, l = t & 63, q = l >> 4, ln = l & 15;
    const int arow = 16 * w + ln;

    __shared__ unsigned short Bsh[2][8][512];   // 16 KB: [kk][frag][lane*8+j]

    const unsigned short* __restrict__ wbase = wfrag + (size_t)which * 524288;

#define AADDR(ks) (Mbt + q * 8 + ((which == 0) \
        ? (arow * NFK + (ks) * 32) \
        : ((((ks) >> 1) * NFK) + arow * 64 + (((ks) & 1) * 32))))

    const int ks0 = kc * ksc;
    const int ngroups = ksc >> 1;       // 2 ksteps per group (even count)

    f32x4 acc[4];
    #pragma unroll
    for (int ct = 0; ct < 4; ++ct) acc[ct] = (f32x4)0.f;

    float4 A0[2][2], A1[2][2];

    // prologue: B[0] regs -> LDS; A[0] -> A0
    {
        s16x8 Bn[4];
        #pragma unroll
        for (int kk = 0; kk < 2; ++kk)
            #pragma unroll
            for (int ii = 0; ii < 2; ++ii)
                Bn[kk * 2 + ii] = *(const s16x8*)(wbase + CHUNK(w + ii * 4, ks0 + kk) + l * 8);
        #pragma unroll
        for (int kk = 0; kk < 2; ++kk) {
            const float* ap = AADDR(ks0 + kk);
            A0[kk][0] = *(const float4*)ap;
            A0[kk][1] = *(const float4*)(ap + 4);
        }
        #pragma unroll
        for (int kk = 0; kk < 2; ++kk)
            #pragma unroll
            for (int ii = 0; ii < 2; ++ii)
                *(s16x8*)&Bsh[kk][w + ii * 4][l * 8] = Bn[kk * 2 + ii];
        __syncthreads();
    }

    auto do_group = [&](float4 (&Acur)[2][2], float4 (&Anxt)[2][2], int g) {
        const bool more = (g + 1 < ngroups);
        const int ksn = ks0 + (g + 1) * 2;
        s16x8 Bn[4];
        if (more) {
            // B first (older in vmcnt queue), then A prefetch
            #pragma unroll
            for (int kk = 0; kk < 2; ++kk)
                #pragma unroll
                for (int ii = 0; ii < 2; ++ii)
                    Bn[kk * 2 + ii] = *(const s16x8*)(wbase + CHUNK(w + ii * 4, ksn + kk) + l * 8);
            #pragma unroll
            for (int kk = 0; kk < 2; ++kk) {
                const float* ap = AADDR(ksn + kk);
                Anxt[kk][0] = *(const float4*)ap;
                Anxt[kk][1] = *(const float4*)(ap + 4);
            }
        }
        #pragma unroll
        for (int kk = 0; kk < 2; ++kk) {
            s16x8 bh[4], bl[4];
            #pragma unroll
            for (int ct = 0; ct < 4; ++ct) {
                bh[ct] = *(const s16x8*)&Bsh[kk][ct][l * 8];
                bl[ct] = *(const s16x8*)&Bsh[kk][4 + ct][l * 8];
            }
            s16x8 ah, al;
            split8(Acur[kk][0], Acur[kk][1], ah, al);
            #pragma unroll
            for (int ct = 0; ct < 4; ++ct) {
                acc[ct] = MFMA_B16(ah, bh[ct], acc[ct]);
                acc[ct] = MFMA_B16(al, bh[ct], acc[ct]);
                acc[ct] = MFMA_B16(ah, bl[ct], acc[ct]);
            }
        }
        __syncthreads();
        if (more) {
            #pragma unroll
            for (int kk = 0; kk < 2; ++kk)
                #pragma unroll
                for (int ii = 0; ii < 2; ++ii)
                    *(s16x8*)&Bsh[kk][w + ii * 4][l * 8] = Bn[kk * 2 + ii];
            __syncthreads();
        }
    };

    for (int g = 0; g < ngroups; g += 2) {
        do_group(A0, A1, g);
        do_group(A1, A0, g + 1);
    }
#undef AADDR

    float* __restrict__ pout = spart + ((size_t)(kc * 2 + which) * BT + bt) * 4096;
    #pragma unroll
    for (int ct = 0; ct < 4; ++ct)
        #pragma unroll
        for (int reg = 0; reg < 4; ++reg)
            pout[(16 * w + 4 * q + reg) * 64 + 16 * ct + ln] = acc[ct][reg];
}

// ---------------------------------------------------------------------------
// K2b: sum partials + bias -> softmax -> entropy -> top-4 -> psel + rtab.
// grid (128, 2), 256 threads.
// ---------------------------------------------------------------------------
__global__ __launch_bounds__(256) void finalize_kernel(
    const float* __restrict__ spart, const float* __restrict__ beff,
    float* __restrict__ psel, int* __restrict__ rtab, int scc)
{
    const int bt = blockIdx.x, which = blockIdx.y;
    const int t = threadIdx.x;
    const int row = t >> 2, cb = (t & 3) * 16;

    float s[16] = {};
    for (int c = 0; c < scc; ++c) {
        const float* __restrict__ p =
            spart + ((size_t)(c * 2 + which) * BT + bt) * 4096 + row * 64 + cb;
        #pragma unroll
        for (int qq = 0; qq < 4; ++qq) {
            float4 v = *(const float4*)(p + 4 * qq);
            s[4 * qq + 0] += v.x; s[4 * qq + 1] += v.y;
            s[4 * qq + 2] += v.z; s[4 * qq + 3] += v.w;
        }
    }
    #pragma unroll
    for (int jj = 0; jj < 16; ++jj) s[jj] += beff[which * 64 + cb + jj];

    float m = -INFINITY;
    #pragma unroll
    for (int jj = 0; jj < 16; ++jj) m = fmaxf(m, s[jj]);
    m = fmaxf(m, __shfl_xor(m, 1));
    m = fmaxf(m, __shfl_xor(m, 2));

    float e[16], sum = 0.f;
    #pragma unroll
    for (int jj = 0; jj < 16; ++jj) { e[jj] = expf(s[jj] - m); sum += e[jj]; }
    sum += __shfl_xor(sum, 1);
    sum += __shfl_xor(sum, 2);
    const float inv = 1.0f / sum;

    float pv[16], h = 0.f;
    #pragma unroll
    for (int jj = 0; jj < 16; ++jj) {
        pv[jj] = e[jj] * inv;
        h += pv[jj] * logf(pv[jj] + 1e-9f);
    }
    h += __shfl_xor(h, 1);
    h += __shfl_xor(h, 2);
    const float H = -h;

    __shared__ float ent[64];
    __shared__ int sel[4];
    if ((t & 3) == 0) ent[row] = H;
    __syncthreads();
    if (t == 0) {
        unsigned long long used = 0ull;
        for (int ss = 0; ss < 4; ++ss) {
            float best = INFINITY; int bi = 0;
            for (int r = 0; r < 64; ++r) {
                if ((used >> r) & 1ull) continue;
                if (ent[r] < best) { best = ent[r]; bi = r; }
            }
            used |= 1ull << bi;
            sel[ss] = bi;
        }
    }
    __syncthreads();

    int* __restrict__ rt = rtab + ((size_t)which * BT + bt) * 64;
    if (t < 64) rt[t] = -1;
    __syncthreads();
    if (t < 4) rt[sel[t]] = t;

    #pragma unroll
    for (int ss = 0; ss < 4; ++ss) {
        if (row == sel[ss]) {
            float* __restrict__ dp = psel + (((size_t)which * BT + bt) * 4 + ss) * 64 + cb;
            #pragma unroll
            for (int jj = 0; jj < 16; ++jj) dp[jj] = pv[jj];
        }
    }
}

// ---------------------------------------------------------------------------
// K3a: partial over a j-slice: resb2[jh][bt][i][jj][k] contribution.
// grid (128 bt, 4 k-slices of 16 rows, JH j-slices), 256 threads.
// ---------------------------------------------------------------------------
__global__ __launch_bounds__(256) void res_compute(
    const float* __restrict__ M, const float* __restrict__ psel,
    float* __restrict__ resb2, int jrows)
{
    const int bt = blockIdx.x, kc = blockIdx.y, jh = blockIdx.z;
    __shared__ float po[4][64], pd[4][64];
    __shared__ float o1[4][16][68];

    const int t = threadIdx.x;
    {
        int ss = t >> 6, ll = t & 63;
        po[ss][ll] = psel[(((size_t)0 * BT + bt) * 4 + ss) * 64 + ll];
        pd[ss][ll] = psel[(((size_t)1 * BT + bt) * 4 + ss) * 64 + ll];
    }
    __syncthreads();

    const float* __restrict__ Ms =
        M + (size_t)bt * NN * NFK + (size_t)(jh * jrows) * NFK + kc * 1024 + t * 4;

    float4 a0 = {0,0,0,0}, a1 = {0,0,0,0}, a2 = {0,0,0,0}, a3 = {0,0,0,0};
    #pragma unroll 8
    for (int j = 0; j < jrows; ++j) {
        float4 mv = *(const float4*)(Ms + (size_t)j * NFK);
        int jg = jh * jrows + j;
        float w0 = po[0][jg], w1 = po[1][jg], w2 = po[2][jg], w3 = po[3][jg];
        a0.x += w0 * mv.x; a0.y += w0 * mv.y; a0.z += w0 * mv.z; a0.w += w0 * mv.w;
        a1.x += w1 * mv.x; a1.y += w1 * mv.y; a1.z += w1 * mv.z; a1.w += w1 * mv.w;
        a2.x += w2 * mv.x; a2.y += w2 * mv.y; a2.z += w2 * mv.z; a2.w += w2 * mv.w;
        a3.x += w3 * mv.x; a3.y += w3 * mv.y; a3.z += w3 * mv.z; a3.w += w3 * mv.w;
    }
    {
        int kl = t >> 4, l4 = (t & 15) * 4;
        *(float4*)&o1[0][kl][l4] = a0;
        *(float4*)&o1[1][kl][l4] = a1;
        *(float4*)&o1[2][kl][l4] = a2;
        *(float4*)&o1[3][kl][l4] = a3;
    }
    __syncthreads();
    {
        int i = t >> 6, jj = (t >> 4) & 3, k = t & 15;
        float v = 0.f;
        #pragma unroll
        for (int l4 = 0; l4 < 16; ++l4) {
            float4 ov = *(const float4*)&o1[i][k][l4 * 4];
            float4 pvv = *(const float4*)&pd[jj][l4 * 4];
            v += ov.x * pvv.x + ov.y * pvv.y + ov.z * pvv.z + ov.w * pvv.w;
        }
        resb2[((((size_t)jh * BT + bt) * 4 + i) * 4 + jj) * 64 + kc * 16 + k] = v;
    }
}

// ---------------------------------------------------------------------------
// K3b: stream the full output, unit-stride. block b -> (bt=b>>6, i=b&63),
// writes contiguous 16KB tile out[bt,i,:,:] (zeros or summed res rows).
// ---------------------------------------------------------------------------
__global__ __launch_bounds__(256) void writer_kernel(
    const float* __restrict__ resb2, const int* __restrict__ rtab,
    float* __restrict__ out, int jh_n)
{
    const int b = blockIdx.x, bt = b >> 6, i = b & 63;
    const int t = threadIdx.x;
    __shared__ float rl[4][64];
    __shared__ int jdl[64];

    const int ii = rtab[(size_t)bt * 64 + i];
    if (t < 64) jdl[t] = rtab[(size_t)BT * 64 + (size_t)bt * 64 + t];
    if (ii >= 0) {
        int jj = t >> 6, k = t & 63;
        size_t base = (((size_t)bt * 4 + ii) * 4 + jj) * 64 + k;
        float s = 0.f;
        for (int h = 0; h < jh_n; ++h)
            s += resb2[(size_t)h * BT * 1024 + base];
        rl[jj][k] = s;
    }
    __syncthreads();

    float* __restrict__ dst = out + (size_t)b * 4096;
    #pragma unroll
    for (int s = 0; s < 4; ++s) {
        int p = s * 1024 + t * 4;          // unit-stride across the wave
        int jj = p >> 6, k = p & 63;
        float4 v = {0.f, 0.f, 0.f, 0.f};
        if (ii >= 0) {
            int jd = jdl[jj];
            if (jd >= 0) v = *(const float4*)&rl[jd][k];
        }
        *(float4*)(dst + p) = v;
    }
}

// ---------------------------------------------------------------------------
extern "C" void kernel_launch(void* const* d_in, const int* in_sizes, int n_in,
                              void* d_out, int out_size, void* d_ws, size_t ws_size,
                              hipStream_t stream)
{
    const float* M   = (const float*)d_in[0];
    const float* Wo  = (const float*)d_in[1];
    const float* bo  = (const float*)d_in[2];
    const float* Wso = (const float*)d_in[3];
    const float* bso = (const float*)d_in[4];
    const float* Wd  = (const float*)d_in[5];
    const float* bd  = (const float*)d_in[6];
    const float* Wsd = (const float*)d_in[7];
    const float* bsd = (const float*)d_in[8];
    float* out = (float*)d_out;

    float* ws = (float*)d_ws;
    unsigned short* wfrag = (unsigned short*)d_ws;
    float* beff  = ws + BEFF_FOFF;
    float* psel  = ws + PSEL_FOFF;
    int*   rtab  = (int*)(ws + RTAB_FOFF);
    float* resb2 = ws + RES_FOFF;

    // graded config: (FCC, SCC, JH) by available workspace
    int FCC = 4, SCC = 4, JH = 4;
    size_t need = ((size_t)RES_FOFF + (size_t)JH * BT * 1024
                   + (size_t)FCC * 524288 + (size_t)SCC * 1048576) * 4;
    if (ws_size < need) {
        FCC = 2; SCC = 4; JH = 2;
        need = ((size_t)RES_FOFF + (size_t)JH * BT * 1024
                + (size_t)FCC * 524288 + (size_t)SCC * 1048576) * 4;
        if (ws_size < need) { FCC = 1; SCC = 1; JH = 2; }
    }
    float* fpart = resb2 + (size_t)JH * BT * 1024;
    float* spart = fpart + (size_t)FCC * 524288;

    fold_part<<<dim3(128, 2, FCC), 256, 0, stream>>>(Wso, Wo, Wsd, Wd, fpart, NH / FCC);
    fold_reduce<<<dim3(64, 2), 256, 0, stream>>>(fpart, wfrag, FCC,
                                                 Wso, bo, bso, Wsd, bd, bsd, beff);
    scores_part<<<dim3(BT, 2, SCC), 256, 0, stream>>>(M, wfrag, spart, 128 / SCC);
    finalize_kernel<<<dim3(BT, 2), 256, 0, stream>>>(spart, beff, psel, rtab, SCC);
    res_compute<<<dim3(BT, 4, JH), 256, 0, stream>>>(M, psel, resb2, NN / JH);
    writer_kernel<<<BT * 64, 256, 0, stream>>>(resb2, rtab, out, JH);
}